// Round 1
// baseline (883.839 us; speedup 1.0000x reference)
//
#include <hip/hip_runtime.h>
#include <cstdint>
#include <cstddef>

typedef unsigned long long u64;
typedef unsigned int u32;

#define R_ANCH 96000
#define NIMG   8
#define KMIX   5
#define PRE    2000
#define POST   1000
#define NGT    32
#define NCHUNK 375   // R_ANCH / 256

#define IMG_SZ        1280.0f
#define NMS_T         0.7f
#define SCALE_CLAMP_F 4.135166556742356f
#define HALF_L2PI     0.9189385332046727f

__device__ __forceinline__ u64 make_key(float s, int r) {
  u32 u = __float_as_uint(s);
  u = (u & 0x80000000u) ? ~u : (u | 0x80000000u);
  return ((u64)u << 32) | (u64)(0xFFFFFFFFu - (u32)r);
}

__device__ __forceinline__ float dec_score(u64 key) {
  u32 o = (u32)(key >> 32);
  u32 bits = (o & 0x80000000u) ? (o ^ 0x80000000u) : ~o;
  return __uint_as_float(bits);
}

// contract(off): kL1 and kL2 must produce bit-identical IoU values so that
// "iou >= best_gt - 1e-7" behaves exactly like the reference (same-array compare).
__device__ __forceinline__ float iou_pair(float a0,float a1,float a2,float a3,
                                          float b0,float b1,float b2,float b3) {
#pragma clang fp contract(off)
  float areaA = (a2-a0)*(a3-a1);
  float areaB = (b2-b0)*(b3-b1);
  float lx=fmaxf(a0,b0), ly=fmaxf(a1,b1);
  float rx=fminf(a2,b2), ry=fminf(a3,b3);
  float iw=fmaxf(rx-lx,0.0f), ih=fmaxf(ry-ly,0.0f);
  float inter=iw*ih;
  return inter / fmaxf(areaA+areaB-inter, 1e-9f);
}

__device__ __forceinline__ u64 shfl64(u64 v, int src) {
  int lo = __shfl((int)(u32)v, src, 64);
  int hi = __shfl((int)(u32)(v>>32), src, 64);
  return ((u64)(u32)hi<<32)|(u64)(u32)lo;
}

// ---------------- init: zero global accumulators --------------------------
__global__ void kInit(int* best, float* acc) {
  int t = blockIdx.x*64 + threadIdx.x;
  if (t < NIMG*NGT) best[t] = 0;           // 0 == 0.0f bits, iou >= 0
  if (t < 2) acc[t] = 0.0f;
}

// ---------------- A: MDN softmax moments ----------------------------------
__global__ __launch_bounds__(256) void kA_mdn(
    const float* __restrict__ pi, const float* __restrict__ mu,
    const float* __restrict__ sigma, float* __restrict__ logits,
    float* __restrict__ epis, float* __restrict__ alea) {
  int r = blockIdx.x*256 + threadIdx.x;
  int img = blockIdx.y;
  size_t base = (size_t)img*KMIX*R_ANCH + r;
  float p[KMIX], m[KMIX], s[KMIX];
#pragma unroll
  for (int k=0;k<KMIX;k++){
    p[k]=pi[base+(size_t)k*R_ANCH];
    m[k]=mu[base+(size_t)k*R_ANCH];
    s[k]=sigma[base+(size_t)k*R_ANCH];
  }
  float mx = p[0];
#pragma unroll
  for (int k=1;k<KMIX;k++) mx = fmaxf(mx,p[k]);
  float e[KMIX]; float sum = 0.0f;
#pragma unroll
  for (int k=0;k<KMIX;k++){ e[k]=expf(p[k]-mx); sum += e[k]; }
  float w[KMIX]; float lg = 0.0f;
#pragma unroll
  for (int k=0;k<KMIX;k++){ w[k]=e[k]/sum; lg += w[k]*m[k]; }
  float ep = 0.0f, al = 0.0f;
#pragma unroll
  for (int k=0;k<KMIX;k++){ float d=m[k]-lg; ep += w[k]*d*d; al += w[k]*s[k]*s[k]; }
  size_t o = (size_t)img*R_ANCH + r;
  logits[o]=lg; epis[o]=ep; alea[o]=al;
}

// ---------------- B: exact top-2000 (radix-select + bitonic) + gather -----
__global__ __launch_bounds__(1024) void kB_topk(
    const float* __restrict__ logits, const float* __restrict__ epis,
    const float* __restrict__ alea, const float* __restrict__ deltas,
    const float* __restrict__ anchors,
    float* __restrict__ tb, float* __restrict__ tu, float* __restrict__ ts) {
  __shared__ u64 s_keys[2048];
  __shared__ u32 s_hist[256];
  __shared__ u64 s_prefix, s_thresh;
  __shared__ int s_nbits, s_k, s_done;
  __shared__ u32 s_cnt;
  int tid = threadIdx.x, img = blockIdx.x;
  const float* sc = logits + (size_t)img*R_ANCH;
  if (tid==0){ s_prefix=0; s_nbits=0; s_k=PRE; s_done=0; s_cnt=0; }
  __syncthreads();
  for (int round=0; round<8; ++round){
    if (s_done) break;                       // block-uniform
    if (tid < 256) s_hist[tid]=0;
    __syncthreads();
    int nb = s_nbits; u64 pref = s_prefix;
    int shift = 56 - 8*round;
    for (int r=tid; r<R_ANCH; r+=1024){
      u64 key = make_key(sc[r], r);
      if (nb==0 || (key >> (64-nb)) == pref)
        atomicAdd(&s_hist[(u32)(key>>shift)&255u], 1u);
    }
    __syncthreads();
    if (tid==0){
      int kk = s_k; int chosen = 0; u32 c = 0;
      for (int d=255; d>=0; --d){
        c = s_hist[d];
        if (kk <= (int)c){ chosen = d; break; }
        kk -= (int)c;
      }
      s_prefix = (s_prefix<<8) | (u64)chosen;
      s_nbits += 8; s_k = kk;
      if (c == 1u) s_done = 1;               // unique key with this prefix
    }
    __syncthreads();
  }
  if (s_done){                               // find the unique matching key
    int nb = s_nbits; u64 pref = s_prefix;
    for (int r=tid; r<R_ANCH; r+=1024){
      u64 key = make_key(sc[r], r);
      if ((key >> (64-nb)) == pref) s_thresh = key;
    }
  } else if (tid==0) s_thresh = s_prefix;    // 64 bits resolved
  __syncthreads();
  u64 thr = s_thresh;
  for (int r=tid; r<R_ANCH; r+=1024){        // gather: exactly PRE keys >= thr
    u64 key = make_key(sc[r], r);
    if (key >= thr){
      u32 p = atomicAdd(&s_cnt, 1u);
      if (p < 2048u) s_keys[p] = key;
    }
  }
  __syncthreads();
  for (int p = PRE + tid; p < 2048; p += 1024) s_keys[p] = 0ull;
  __syncthreads();
  // bitonic sort, descending, 2048 elems / 1024 threads
  for (u32 kk=2; kk<=2048; kk<<=1){
    for (u32 j=kk>>1; j>0; j>>=1){
      u32 i = (((u32)tid & ~(j-1u)) << 1) | ((u32)tid & (j-1u));
      u32 p = i | j;
      u64 a = s_keys[i], b = s_keys[p];
      bool descSeg = ((i & kk) == 0u);
      bool sw = descSeg ? (a < b) : (a > b);
      if (sw){ s_keys[i]=b; s_keys[p]=a; }
      __syncthreads();
    }
  }
  // decode + apply_deltas + clip + gather uncertainty
  for (int p=tid; p<PRE; p+=1024){
    u64 key = s_keys[p];
    u32 idx = 0xFFFFFFFFu - (u32)(key & 0xFFFFFFFFull);
    ts[img*PRE + p] = dec_score(key);
    float4 a = ((const float4*)anchors)[idx];
    float4 d = ((const float4*)deltas)[(size_t)img*R_ANCH + idx];
    float w = a.z - a.x, h = a.w - a.y;
    float cx = a.x + 0.5f*w, cy = a.y + 0.5f*h;
    float dw = fminf(d.z, SCALE_CLAMP_F), dh = fminf(d.w, SCALE_CLAMP_F);
    float pcx = d.x*w + cx, pcy = d.y*h + cy;
    float pw = expf(dw)*w, ph = expf(dh)*h;
    float x0 = fminf(fmaxf(pcx - 0.5f*pw, 0.0f), IMG_SZ);
    float y0 = fminf(fmaxf(pcy - 0.5f*ph, 0.0f), IMG_SZ);
    float x1 = fminf(fmaxf(pcx + 0.5f*pw, 0.0f), IMG_SZ);
    float y1 = fminf(fmaxf(pcy + 0.5f*ph, 0.0f), IMG_SZ);
    ((float4*)tb)[(size_t)img*PRE + p] = make_float4(x0,y0,x1,y1);
    size_t o = (size_t)img*R_ANCH + idx;
    ((float2*)tu)[(size_t)img*PRE + p] = make_float2(epis[o], alea[o]);
  }
}

// ---------------- D: suppression bitmask (2000x2000 bits) -----------------
__global__ __launch_bounds__(256) void kD_mask(const float* __restrict__ tb,
                                               u64* __restrict__ mask) {
  __shared__ float4 s_box[PRE];              // 32 KB
  int tid = threadIdx.x, img = blockIdx.y;
  const float4* tbi = (const float4*)tb + (size_t)img*PRE;
  for (int q=tid; q<PRE; q+=256) s_box[q] = tbi[q];
  __syncthreads();
  int wave = tid >> 6, lane = tid & 63;
  int i = blockIdx.x*4 + wave;               // gridDim.x = 500
  float4 A = s_box[i];
  u64* row = mask + ((size_t)img*PRE + i)*32;
  for (int w=0; w<32; ++w){
    int j = w*64 + lane;
    bool bit = false;
    if (j < PRE){
      float4 B = s_box[j];
      float v = iou_pair(A.x,A.y,A.z,A.w, B.x,B.y,B.z,B.w);
      bit = (v > NMS_T) && (j > i);
    }
    u64 m = __ballot(bit);
    if (lane==0) row[w] = m;
  }
}

// ---------------- E: sequential greedy NMS, one wave per image ------------
__global__ __launch_bounds__(64) void kE_nms(const u64* __restrict__ mask,
                                             u64* __restrict__ keep) {
  __shared__ u64 s_rows[64*32];              // 16 KB
  __shared__ u64 s_rem[32];
  int img = blockIdx.x, lane = threadIdx.x;
  if (lane < 32) s_rem[lane] = 0ull;
  __syncthreads();
  for (int t=0; t<32; ++t){
    int base = t*64;
    int cnt = min(64, PRE - base);
    const u64* g = mask + ((size_t)img*PRE + base)*32;
    for (int q=lane; q<cnt*32; q+=64) s_rows[q] = g[q];
    __syncthreads();
    u64 W = s_rem[t];                        // broadcast
    u64 myRowT = (lane < cnt) ? s_rows[lane*32 + t] : 0ull;
    u64 nz = __ballot(myRowT != 0ull);
    u64 K = 0ull;
    for (int b=0; b<cnt; ++b){               // wave-uniform serial chain
      if (!((W>>b)&1ull)){
        K |= (1ull<<b);
        if ((nz>>b)&1ull) W |= shfl64(myRowT, b);
      }
    }
    if (lane < 32){
      u64 acc = 0ull, kk = K;
      while (kk){
        int b = __builtin_ctzll(kk); kk &= kk-1ull;
        acc |= s_rows[b*32 + lane];
      }
      s_rem[lane] |= acc;                    // word t: old|acc_t == W (consistent)
    }
    __syncthreads();
  }
  if (lane < 32) keep[img*32 + lane] = ~s_rem[lane];
}

// ---------------- L1: best IoU per GT over all anchors --------------------
__global__ __launch_bounds__(256) void kL1_bestgt(const float* __restrict__ anchors,
                                                  const float* __restrict__ gt,
                                                  int* __restrict__ best) {
  __shared__ float s_gt[NGT*4];
  __shared__ int s_best[NGT];
  int tid = threadIdx.x, img = blockIdx.y;
  int r = blockIdx.x*256 + tid;
  if (tid < NGT*4) s_gt[tid] = gt[img*NGT*4 + tid];
  if (tid < NGT) s_best[tid] = 0;
  __syncthreads();
  float4 a = ((const float4*)anchors)[r];
#pragma unroll 4
  for (int g=0; g<NGT; ++g){
    float v = iou_pair(s_gt[g*4],s_gt[g*4+1],s_gt[g*4+2],s_gt[g*4+3],
                       a.x,a.y,a.z,a.w);
    if (v > __int_as_float(s_best[g])) atomicMax(&s_best[g], __float_as_int(v));
  }
  __syncthreads();
  if (tid < NGT) atomicMax(&best[img*NGT + tid], s_best[tid]);
}

// ---------------- L2: labels, NLL, L1-loc, per-chunk pos/neg counts -------
__global__ __launch_bounds__(256) void kL2_label(
    const float* __restrict__ anchors, const float* __restrict__ gt,
    const int* __restrict__ best, const float* __restrict__ pi,
    const float* __restrict__ mu, const float* __restrict__ sigma,
    const float* __restrict__ deltas,
    signed char* __restrict__ label, float* __restrict__ nll_o,
    float* __restrict__ loc_o, int* __restrict__ cpos, int* __restrict__ cneg) {
  __shared__ float s_gt[NGT*4];
  __shared__ float s_bg[NGT];
  __shared__ int s_w[8];
  int tid = threadIdx.x, img = blockIdx.y;
  int r = blockIdx.x*256 + tid;
  if (tid < NGT*4) s_gt[tid] = gt[img*NGT*4 + tid];
  if (tid < NGT) s_bg[tid] = __int_as_float(best[img*NGT + tid]);
  __syncthreads();
  float4 a = ((const float4*)anchors)[r];
  float vbest = -1.0f; int idx = 0; bool lq = false;
#pragma unroll 4
  for (int g=0; g<NGT; ++g){
    float v = iou_pair(s_gt[g*4],s_gt[g*4+1],s_gt[g*4+2],s_gt[g*4+3],
                       a.x,a.y,a.z,a.w);
    if (v > vbest){ vbest = v; idx = g; }    // first-index argmax
    float bg = s_bg[g];
    lq = lq || ((v >= bg - 1e-7f) && (bg > 0.0f));
  }
  int lab = lq ? 1 : (vbest >= 0.7f ? 1 : (vbest >= 0.3f ? -1 : 0));
  // NLL
  size_t base = (size_t)img*KMIX*R_ANCH + r;
  float p[KMIX], m[KMIX], s[KMIX];
#pragma unroll
  for (int k=0;k<KMIX;k++){
    p[k]=pi[base+(size_t)k*R_ANCH];
    m[k]=mu[base+(size_t)k*R_ANCH];
    s[k]=sigma[base+(size_t)k*R_ANCH];
  }
  float mx = p[0];
#pragma unroll
  for (int k=1;k<KMIX;k++) mx = fmaxf(mx,p[k]);
  float sum = 0.0f;
#pragma unroll
  for (int k=0;k<KMIX;k++) sum += expf(p[k]-mx);
  float lsum = logf(sum);
  float t_ = fminf(fmaxf(vbest, 0.0f), 1.0f);
  float comp[KMIX];
#pragma unroll
  for (int k=0;k<KMIX;k++){
    float z = (t_ - m[k]) / s[k];
    comp[k] = (p[k]-mx-lsum) - 0.5f*z*z - logf(s[k]) - HALF_L2PI;
  }
  float cm = comp[0];
#pragma unroll
  for (int k=1;k<KMIX;k++) cm = fmaxf(cm, comp[k]);
  float se = 0.0f;
#pragma unroll
  for (int k=0;k<KMIX;k++) se += expf(comp[k]-cm);
  float nll = -(cm + logf(se));
  // loc L1 vs matched gt
  const float* gb = &s_gt[idx*4];
  float sw = a.z-a.x, sh = a.w-a.y;
  float scx = a.x+0.5f*sw, scy = a.y+0.5f*sh;
  float tw = gb[2]-gb[0], th = gb[3]-gb[1];
  float tcx = gb[0]+0.5f*tw, tcy = gb[1]+0.5f*th;
  float4 d = ((const float4*)deltas)[(size_t)img*R_ANCH + r];
  float loc = fabsf(d.x-(tcx-scx)/sw) + fabsf(d.y-(tcy-scy)/sh)
            + fabsf(d.z-logf(tw/sw)) + fabsf(d.w-logf(th/sh));
  size_t o = (size_t)img*R_ANCH + r;
  label[o] = (signed char)lab; nll_o[o] = nll; loc_o[o] = loc;
  // per-chunk pos/neg counts
  u64 bp = __ballot(lab==1), bn = __ballot(lab==0);
  int wid = tid>>6, lane = tid&63;
  if (lane==0){ s_w[wid*2]=__popcll(bp); s_w[wid*2+1]=__popcll(bn); }
  __syncthreads();
  if (tid==0){
    cpos[img*NCHUNK + blockIdx.x] = s_w[0]+s_w[2]+s_w[4]+s_w[6];
    cneg[img*NCHUNK + blockIdx.x] = s_w[1]+s_w[3]+s_w[5]+s_w[7];
  }
}

// ---------------- L3: per-image chunk-offset scan + quotas ----------------
__global__ void kL3_scan(const int* __restrict__ cpos, const int* __restrict__ cneg,
                         int* __restrict__ opos, int* __restrict__ oneg,
                         int* __restrict__ quota) {
  int img = blockIdx.x;
  if (threadIdx.x == 0){
    int tp=0, tn=0;
    for (int c=0; c<NCHUNK; ++c){
      opos[img*NCHUNK+c]=tp; tp += cpos[img*NCHUNK+c];
      oneg[img*NCHUNK+c]=tn; tn += cneg[img*NCHUNK+c];
    }
    int np = tp < 128 ? tp : 128;
    quota[img*2] = np; quota[img*2+1] = 256 - np;
  }
}

// ---------------- L4: quota-sampled loss accumulation ---------------------
__global__ __launch_bounds__(256) void kL4_accum(
    const signed char* __restrict__ label, const float* __restrict__ nll_i,
    const float* __restrict__ loc_i, const int* __restrict__ opos,
    const int* __restrict__ oneg, const int* __restrict__ quota,
    float* __restrict__ acc) {
  __shared__ int s_wp[4], s_wn[4];
  __shared__ float s_red[8];
  int tid = threadIdx.x, img = blockIdx.y;
  int r = blockIdx.x*256 + tid;
  size_t o = (size_t)img*R_ANCH + r;
  int lab = label[o];
  bool pos = (lab==1), neg = (lab==0);
  u64 bp = __ballot(pos), bn = __ballot(neg);
  int wid = tid>>6, lane = tid&63;
  if (lane==0){ s_wp[wid]=__popcll(bp); s_wn[wid]=__popcll(bn); }
  __syncthreads();
  int pre_p = opos[img*NCHUNK + blockIdx.x];
  int pre_n = oneg[img*NCHUNK + blockIdx.x];
  for (int w=0; w<wid; ++w){ pre_p += s_wp[w]; pre_n += s_wn[w]; }
  u64 lm = (1ull<<lane) - 1ull;
  pre_p += __popcll(bp & lm);
  pre_n += __popcll(bn & lm);
  int np = quota[img*2], nn = quota[img*2+1];
  bool kp = pos && (pre_p < np);
  bool kn = neg && (pre_n < nn);
  float c_cls = (kp||kn) ? nll_i[o] : 0.0f;
  float c_loc = kp ? loc_i[o] : 0.0f;
  for (int of=32; of>0; of>>=1){
    c_cls += __shfl_down(c_cls, of, 64);
    c_loc += __shfl_down(c_loc, of, 64);
  }
  if (lane==0){ s_red[wid]=c_cls; s_red[4+wid]=c_loc; }
  __syncthreads();
  if (tid==0){
    float a = s_red[0]+s_red[1]+s_red[2]+s_red[3];
    float b = s_red[4]+s_red[5]+s_red[6]+s_red[7];
    if (a != 0.0f) atomicAdd(&acc[0], a);
    if (b != 0.0f) atomicAdd(&acc[1], b);
  }
}

// ---------------- F: stable compaction to 1000 + outputs ------------------
__global__ __launch_bounds__(256) void kF_final(
    const float* __restrict__ tb, const float* __restrict__ tu,
    const float* __restrict__ ts, const u64* __restrict__ keepw,
    const float* __restrict__ acc, float* __restrict__ out) {
  __shared__ int s_wk[4], s_wn[4];
  __shared__ int s_kc, s_runk, s_runn;
  int tid = threadIdx.x, img = blockIdx.x;
  int wid = tid>>6, lane = tid&63;
  const u64* kw = keepw + img*32;
  const float NEG_INF = __uint_as_float(0xff800000u);
  // pass 1: total kept (keep bit && non-degenerate after clip)
  int cnt = 0;
  for (int c=0; c<8; ++c){
    int p = c*256 + tid;
    float4 b = ((const float4*)tb)[(size_t)img*PRE + p];
    bool kp = (((kw[p>>6]>>(p&63))&1ull)!=0ull) && (b.z > b.x) && (b.w > b.y);
    cnt += kp ? 1 : 0;
  }
  for (int of=32; of>0; of>>=1) cnt += __shfl_down(cnt, of, 64);
  if (lane==0) s_wk[wid] = cnt;
  __syncthreads();
  if (tid==0){ s_kc = s_wk[0]+s_wk[1]+s_wk[2]+s_wk[3]; s_runk=0; s_runn=0; }
  __syncthreads();
  int kc = s_kc;
  // pass 2: stable ranks -> scatter (kept first, then -inf fillers)
  for (int c=0; c<8; ++c){
    int p = c*256 + tid;
    float4 b = ((const float4*)tb)[(size_t)img*PRE + p];
    bool kp = (((kw[p>>6]>>(p&63))&1ull)!=0ull) && (b.z > b.x) && (b.w > b.y);
    u64 bk = __ballot(kp), bn = __ballot(!kp);
    if (lane==0){ s_wk[wid]=__popcll(bk); s_wn[wid]=__popcll(bn); }
    __syncthreads();
    int pk = s_runk, pn = s_runn;
    for (int w=0; w<wid; ++w){ pk += s_wk[w]; pn += s_wn[w]; }
    u64 lm = (1ull<<lane) - 1ull;
    pk += __popcll(bk & lm);
    pn += __popcll(bn & lm);
    int slot = kp ? pk : (kc + pn);
    if (slot < POST){
      ((float4*)out)[img*POST + slot] = b;
      out[32000 + img*POST + slot] = kp ? ts[img*PRE + p] : NEG_INF;
      ((float2*)(out + 40000))[img*POST + slot] = ((const float2*)tu)[(size_t)img*PRE + p];
    }
    __syncthreads();
    if (tid==0){
      s_runk += s_wk[0]+s_wk[1]+s_wk[2]+s_wk[3];
      s_runn += s_wn[0]+s_wn[1]+s_wn[2]+s_wn[3];
    }
    __syncthreads();
  }
  if (img==0 && tid<2) out[56000+tid] = acc[tid] * (1.0f/2048.0f);
}

// ---------------- host-side launch ----------------------------------------
extern "C" void kernel_launch(void* const* d_in, const int* in_sizes, int n_in,
                              void* d_out, int out_size, void* d_ws, size_t ws_size,
                              hipStream_t stream) {
  const float* anchors = (const float*)d_in[0];
  const float* pi      = (const float*)d_in[1];
  const float* mu      = (const float*)d_in[2];
  const float* sigma   = (const float*)d_in[3];
  const float* deltas  = (const float*)d_in[4];
  const float* gt      = (const float*)d_in[5];
  float* out = (float*)d_out;

  char* ws = (char*)d_ws;
  size_t off = 0;
  auto alloc = [&](size_t bytes) -> void* {
    void* p = (void*)(ws + off);
    off += (bytes + 255) & ~(size_t)255;
    return p;
  };
  float* logits = (float*)alloc((size_t)NIMG*R_ANCH*4);
  float* epis   = (float*)alloc((size_t)NIMG*R_ANCH*4);
  float* alea   = (float*)alloc((size_t)NIMG*R_ANCH*4);
  float* tb     = (float*)alloc((size_t)NIMG*PRE*4*4);
  float* tu     = (float*)alloc((size_t)NIMG*PRE*2*4);
  float* ts     = (float*)alloc((size_t)NIMG*PRE*4);
  u64*   mask   = (u64*)  alloc((size_t)NIMG*PRE*32*8);
  u64*   keepw  = (u64*)  alloc((size_t)NIMG*32*8);
  int*   best   = (int*)  alloc((size_t)NIMG*NGT*4);
  int*   cpos   = (int*)  alloc((size_t)NIMG*NCHUNK*4);
  int*   cneg   = (int*)  alloc((size_t)NIMG*NCHUNK*4);
  int*   opos   = (int*)  alloc((size_t)NIMG*NCHUNK*4);
  int*   oneg   = (int*)  alloc((size_t)NIMG*NCHUNK*4);
  int*   quota  = (int*)  alloc((size_t)NIMG*2*4);
  float* acc    = (float*)alloc(8);
  // alias dead regions: logits/epis/alea are last read in kB; L2 runs after B.
  signed char* label = (signed char*)logits;
  float* nll = epis;
  float* loc = alea;

  kInit<<<dim3(4), dim3(64), 0, stream>>>(best, acc);
  kA_mdn<<<dim3(NCHUNK, NIMG), dim3(256), 0, stream>>>(pi, mu, sigma, logits, epis, alea);
  kB_topk<<<dim3(NIMG), dim3(1024), 0, stream>>>(logits, epis, alea, deltas, anchors, tb, tu, ts);
  kD_mask<<<dim3(500, NIMG), dim3(256), 0, stream>>>(tb, mask);
  kE_nms<<<dim3(NIMG), dim3(64), 0, stream>>>(mask, keepw);
  kL1_bestgt<<<dim3(NCHUNK, NIMG), dim3(256), 0, stream>>>(anchors, gt, best);
  kL2_label<<<dim3(NCHUNK, NIMG), dim3(256), 0, stream>>>(anchors, gt, best, pi, mu, sigma,
                                                          deltas, label, nll, loc, cpos, cneg);
  kL3_scan<<<dim3(NIMG), dim3(64), 0, stream>>>(cpos, cneg, opos, oneg, quota);
  kL4_accum<<<dim3(NCHUNK, NIMG), dim3(256), 0, stream>>>(label, nll, loc, opos, oneg, quota, acc);
  kF_final<<<dim3(NIMG), dim3(256), 0, stream>>>(tb, tu, ts, keepw, acc, out);
}

// Round 2
// 585.431 us; speedup vs baseline: 1.5097x; 1.5097x over previous
//
#include <hip/hip_runtime.h>
#include <cstdint>
#include <cstddef>

typedef unsigned long long u64;
typedef unsigned int u32;

#define R_ANCH 96000
#define NIMG   8
#define KMIX   5
#define PRE    2000
#define POST   1000
#define NGT    32
#define NCHUNK 375   // R_ANCH / 256

#define IMG_SZ        1280.0f
#define NMS_T         0.7f
#define SCALE_CLAMP_F 4.135166556742356f
#define HALF_L2PI     0.9189385332046727f

__device__ __forceinline__ u64 make_key(float s, int r) {
  u32 u = __float_as_uint(s);
  u = (u & 0x80000000u) ? ~u : (u | 0x80000000u);
  return ((u64)u << 32) | (u64)(0xFFFFFFFFu - (u32)r);
}

__device__ __forceinline__ float dec_score(u64 key) {
  u32 o = (u32)(key >> 32);
  u32 bits = (o & 0x80000000u) ? (o ^ 0x80000000u) : ~o;
  return __uint_as_float(bits);
}

// contract(off): kL1 and kL2 must produce bit-identical IoU values so that
// "iou >= best_gt - 1e-7" behaves exactly like the reference (same-array compare).
__device__ __forceinline__ float iou_pair(float a0,float a1,float a2,float a3,
                                          float b0,float b1,float b2,float b3) {
#pragma clang fp contract(off)
  float areaA = (a2-a0)*(a3-a1);
  float areaB = (b2-b0)*(b3-b1);
  float lx=fmaxf(a0,b0), ly=fmaxf(a1,b1);
  float rx=fminf(a2,b2), ry=fminf(a3,b3);
  float iw=fmaxf(rx-lx,0.0f), ih=fmaxf(ry-ly,0.0f);
  float inter=iw*ih;
  return inter / fmaxf(areaA+areaB-inter, 1e-9f);
}

__device__ __forceinline__ u64 shfl64(u64 v, int src) {
  int lo = __shfl((int)(u32)v, src, 64);
  int hi = __shfl((int)(u32)(v>>32), src, 64);
  return ((u64)(u32)hi<<32)|(u64)(u32)lo;
}

__device__ __forceinline__ u64 shfl64_xor(u64 v, int m) {
  int lo = __shfl_xor((int)(u32)v, m, 64);
  int hi = __shfl_xor((int)(u32)(v>>32), m, 64);
  return ((u64)(u32)hi<<32)|(u64)(u32)lo;
}

// ---------------- init: zero global accumulators --------------------------
__global__ void kInit(int* best, float* acc) {
  int t = blockIdx.x*64 + threadIdx.x;
  if (t < NIMG*NGT) best[t] = 0;           // 0 == 0.0f bits, iou >= 0
  if (t < 2) acc[t] = 0.0f;
}

// ---------------- A: MDN softmax moments ----------------------------------
__global__ __launch_bounds__(256) void kA_mdn(
    const float* __restrict__ pi, const float* __restrict__ mu,
    const float* __restrict__ sigma, float* __restrict__ logits,
    float* __restrict__ epis, float* __restrict__ alea) {
  int r = blockIdx.x*256 + threadIdx.x;
  int img = blockIdx.y;
  size_t base = (size_t)img*KMIX*R_ANCH + r;
  float p[KMIX], m[KMIX], s[KMIX];
#pragma unroll
  for (int k=0;k<KMIX;k++){
    p[k]=pi[base+(size_t)k*R_ANCH];
    m[k]=mu[base+(size_t)k*R_ANCH];
    s[k]=sigma[base+(size_t)k*R_ANCH];
  }
  float mx = p[0];
#pragma unroll
  for (int k=1;k<KMIX;k++) mx = fmaxf(mx,p[k]);
  float e[KMIX]; float sum = 0.0f;
#pragma unroll
  for (int k=0;k<KMIX;k++){ e[k]=expf(p[k]-mx); sum += e[k]; }
  float w[KMIX]; float lg = 0.0f;
#pragma unroll
  for (int k=0;k<KMIX;k++){ w[k]=e[k]/sum; lg += w[k]*m[k]; }
  float ep = 0.0f, al = 0.0f;
#pragma unroll
  for (int k=0;k<KMIX;k++){ float d=m[k]-lg; ep += w[k]*d*d; al += w[k]*s[k]*s[k]; }
  size_t o = (size_t)img*R_ANCH + r;
  logits[o]=lg; epis[o]=ep; alea[o]=al;
}

// ---------------- B: exact top-2000 (radix-select + bitonic) + gather -----
__global__ __launch_bounds__(1024) void kB_topk(
    const float* __restrict__ logits, const float* __restrict__ epis,
    const float* __restrict__ alea, const float* __restrict__ deltas,
    const float* __restrict__ anchors,
    float* __restrict__ tb, float* __restrict__ tu, float* __restrict__ ts) {
  __shared__ u64 s_keys[2048];
  __shared__ u32 s_hist[256];
  __shared__ u64 s_prefix, s_thresh;
  __shared__ int s_nbits, s_k, s_done;
  __shared__ u32 s_cnt;
  int tid = threadIdx.x, img = blockIdx.x;
  const float* sc = logits + (size_t)img*R_ANCH;
  if (tid==0){ s_prefix=0; s_nbits=0; s_k=PRE; s_done=0; s_cnt=0; }
  __syncthreads();
  for (int round=0; round<8; ++round){
    if (s_done) break;                       // block-uniform
    if (tid < 256) s_hist[tid]=0;
    __syncthreads();
    int nb = s_nbits; u64 pref = s_prefix;
    int shift = 56 - 8*round;
    for (int r=tid; r<R_ANCH; r+=1024){
      u64 key = make_key(sc[r], r);
      if (nb==0 || (key >> (64-nb)) == pref)
        atomicAdd(&s_hist[(u32)(key>>shift)&255u], 1u);
    }
    __syncthreads();
    if (tid==0){
      int kk = s_k; int chosen = 0; u32 c = 0;
      for (int d=255; d>=0; --d){
        c = s_hist[d];
        if (kk <= (int)c){ chosen = d; break; }
        kk -= (int)c;
      }
      s_prefix = (s_prefix<<8) | (u64)chosen;
      s_nbits += 8; s_k = kk;
      if (c == 1u) s_done = 1;               // unique key with this prefix
    }
    __syncthreads();
  }
  if (s_done){                               // find the unique matching key
    int nb = s_nbits; u64 pref = s_prefix;
    for (int r=tid; r<R_ANCH; r+=1024){
      u64 key = make_key(sc[r], r);
      if ((key >> (64-nb)) == pref) s_thresh = key;
    }
  } else if (tid==0) s_thresh = s_prefix;    // 64 bits resolved
  __syncthreads();
  u64 thr = s_thresh;
  for (int r=tid; r<R_ANCH; r+=1024){        // gather: exactly PRE keys >= thr
    u64 key = make_key(sc[r], r);
    if (key >= thr){
      u32 p = atomicAdd(&s_cnt, 1u);
      if (p < 2048u) s_keys[p] = key;
    }
  }
  __syncthreads();
  for (int p = PRE + tid; p < 2048; p += 1024) s_keys[p] = 0ull;
  __syncthreads();
  // bitonic sort, descending, 2048 elems / 1024 threads
  for (u32 kk=2; kk<=2048; kk<<=1){
    for (u32 j=kk>>1; j>0; j>>=1){
      u32 i = (((u32)tid & ~(j-1u)) << 1) | ((u32)tid & (j-1u));
      u32 p = i | j;
      u64 a = s_keys[i], b = s_keys[p];
      bool descSeg = ((i & kk) == 0u);
      bool sw = descSeg ? (a < b) : (a > b);
      if (sw){ s_keys[i]=b; s_keys[p]=a; }
      __syncthreads();
    }
  }
  // decode + apply_deltas + clip + gather uncertainty
  for (int p=tid; p<PRE; p+=1024){
    u64 key = s_keys[p];
    u32 idx = 0xFFFFFFFFu - (u32)(key & 0xFFFFFFFFull);
    ts[img*PRE + p] = dec_score(key);
    float4 a = ((const float4*)anchors)[idx];
    float4 d = ((const float4*)deltas)[(size_t)img*R_ANCH + idx];
    float w = a.z - a.x, h = a.w - a.y;
    float cx = a.x + 0.5f*w, cy = a.y + 0.5f*h;
    float dw = fminf(d.z, SCALE_CLAMP_F), dh = fminf(d.w, SCALE_CLAMP_F);
    float pcx = d.x*w + cx, pcy = d.y*h + cy;
    float pw = expf(dw)*w, ph = expf(dh)*h;
    float x0 = fminf(fmaxf(pcx - 0.5f*pw, 0.0f), IMG_SZ);
    float y0 = fminf(fmaxf(pcy - 0.5f*ph, 0.0f), IMG_SZ);
    float x1 = fminf(fmaxf(pcx + 0.5f*pw, 0.0f), IMG_SZ);
    float y1 = fminf(fmaxf(pcy + 0.5f*ph, 0.0f), IMG_SZ);
    ((float4*)tb)[(size_t)img*PRE + p] = make_float4(x0,y0,x1,y1);
    size_t o = (size_t)img*R_ANCH + idx;
    ((float2*)tu)[(size_t)img*PRE + p] = make_float2(epis[o], alea[o]);
  }
}

// ---------------- D: suppression bitmask (2000x2000 bits) -----------------
__global__ __launch_bounds__(256) void kD_mask(const float* __restrict__ tb,
                                               u64* __restrict__ mask) {
  __shared__ float4 s_box[PRE];              // 32 KB
  int tid = threadIdx.x, img = blockIdx.y;
  const float4* tbi = (const float4*)tb + (size_t)img*PRE;
  for (int q=tid; q<PRE; q+=256) s_box[q] = tbi[q];
  __syncthreads();
  int wave = tid >> 6, lane = tid & 63;
  int i = blockIdx.x*4 + wave;               // gridDim.x = 500
  float4 A = s_box[i];
  u64* row = mask + ((size_t)img*PRE + i)*32;
  for (int w=0; w<32; ++w){
    int j = w*64 + lane;
    bool bit = false;
    if (j < PRE){
      float4 B = s_box[j];
      float v = iou_pair(A.x,A.y,A.z,A.w, B.x,B.y,B.z,B.w);
      bit = (v > NMS_T) && (j > i);
    }
    u64 m = __ballot(bit);
    if (lane==0) row[w] = m;
  }
}

// ---------------- E: greedy NMS, 16 waves per image -----------------------
// Wave 0 runs the unavoidable serial 64-step chain per tile; all 16 waves
// then OR the kept rows' suppression words into s_sup in parallel
// (wave w owns words {w, w+16}, 6-step shfl_xor OR-reduction).
__global__ __launch_bounds__(1024) void kE_nms(const u64* __restrict__ mask,
                                               u64* __restrict__ keep) {
  __shared__ u64 s_sup[32];
  __shared__ u64 s_K;
  int img = blockIdx.x;
  int tid = threadIdx.x, wv = tid>>6, lane = tid&63;
  if (tid < 32) s_sup[tid] = 0ull;
  __syncthreads();
  const u64* M = mask + (size_t)img*PRE*32;
  for (int t=0; t<32; ++t){
    int base = t*64;
    int cnt = min(64, PRE - base);           // last tile: 16
    if (wv == 0){
      u64 myRowT = (lane < cnt) ? M[(size_t)(base+lane)*32 + t] : 0ull;
      u64 nz = __ballot(myRowT != 0ull);
      u64 W = s_sup[t];                      // wave-uniform
      u64 K = 0ull;
      for (int b=0; b<cnt; ++b){
        if (!((W>>b)&1ull)){
          K |= (1ull<<b);
          if ((nz>>b)&1ull) W |= shfl64(myRowT, b);
        }
      }
      if (lane==0){ s_K = K; s_sup[t] = W; } // W = final word t (cross+in-tile)
    }
    __syncthreads();
    u64 K = s_K;
    bool kept = (lane < cnt) && ((K>>lane)&1ull);
    for (int wsel = wv; wsel < 32; wsel += 16){
      if (wsel <= t) continue;               // words <= t already finalized
      u64 v = kept ? M[(size_t)(base+lane)*32 + wsel] : 0ull;
      v |= shfl64_xor(v, 1);
      v |= shfl64_xor(v, 2);
      v |= shfl64_xor(v, 4);
      v |= shfl64_xor(v, 8);
      v |= shfl64_xor(v, 16);
      v |= shfl64_xor(v, 32);
      if (lane==0) s_sup[wsel] |= v;         // single writer per word
    }
    __syncthreads();
  }
  if (tid < 32) keep[img*32 + tid] = ~s_sup[tid];
}

// ---------------- L1: best IoU per GT over all anchors --------------------
__global__ __launch_bounds__(256) void kL1_bestgt(const float* __restrict__ anchors,
                                                  const float* __restrict__ gt,
                                                  int* __restrict__ best) {
  __shared__ float s_gt[NGT*4];
  __shared__ int s_best[NGT];
  int tid = threadIdx.x, img = blockIdx.y;
  int r = blockIdx.x*256 + tid;
  if (tid < NGT*4) s_gt[tid] = gt[img*NGT*4 + tid];
  if (tid < NGT) s_best[tid] = 0;
  __syncthreads();
  float4 a = ((const float4*)anchors)[r];
#pragma unroll 4
  for (int g=0; g<NGT; ++g){
    float v = iou_pair(s_gt[g*4],s_gt[g*4+1],s_gt[g*4+2],s_gt[g*4+3],
                       a.x,a.y,a.z,a.w);
    if (v > __int_as_float(s_best[g])) atomicMax(&s_best[g], __float_as_int(v));
  }
  __syncthreads();
  if (tid < NGT) atomicMax(&best[img*NGT + tid], s_best[tid]);
}

// ---------------- L2: labels, NLL, L1-loc, per-chunk pos/neg counts -------
__global__ __launch_bounds__(256) void kL2_label(
    const float* __restrict__ anchors, const float* __restrict__ gt,
    const int* __restrict__ best, const float* __restrict__ pi,
    const float* __restrict__ mu, const float* __restrict__ sigma,
    const float* __restrict__ deltas,
    signed char* __restrict__ label, float* __restrict__ nll_o,
    float* __restrict__ loc_o, int* __restrict__ cpos, int* __restrict__ cneg) {
  __shared__ float s_gt[NGT*4];
  __shared__ float s_bg[NGT];
  __shared__ int s_w[8];
  int tid = threadIdx.x, img = blockIdx.y;
  int r = blockIdx.x*256 + tid;
  if (tid < NGT*4) s_gt[tid] = gt[img*NGT*4 + tid];
  if (tid < NGT) s_bg[tid] = __int_as_float(best[img*NGT + tid]);
  __syncthreads();
  float4 a = ((const float4*)anchors)[r];
  float vbest = -1.0f; int idx = 0; bool lq = false;
#pragma unroll 4
  for (int g=0; g<NGT; ++g){
    float v = iou_pair(s_gt[g*4],s_gt[g*4+1],s_gt[g*4+2],s_gt[g*4+3],
                       a.x,a.y,a.z,a.w);
    if (v > vbest){ vbest = v; idx = g; }    // first-index argmax
    float bg = s_bg[g];
    lq = lq || ((v >= bg - 1e-7f) && (bg > 0.0f));
  }
  int lab = lq ? 1 : (vbest >= 0.7f ? 1 : (vbest >= 0.3f ? -1 : 0));
  // NLL
  size_t base = (size_t)img*KMIX*R_ANCH + r;
  float p[KMIX], m[KMIX], s[KMIX];
#pragma unroll
  for (int k=0;k<KMIX;k++){
    p[k]=pi[base+(size_t)k*R_ANCH];
    m[k]=mu[base+(size_t)k*R_ANCH];
    s[k]=sigma[base+(size_t)k*R_ANCH];
  }
  float mx = p[0];
#pragma unroll
  for (int k=1;k<KMIX;k++) mx = fmaxf(mx,p[k]);
  float sum = 0.0f;
#pragma unroll
  for (int k=0;k<KMIX;k++) sum += expf(p[k]-mx);
  float lsum = logf(sum);
  float t_ = fminf(fmaxf(vbest, 0.0f), 1.0f);
  float comp[KMIX];
#pragma unroll
  for (int k=0;k<KMIX;k++){
    float z = (t_ - m[k]) / s[k];
    comp[k] = (p[k]-mx-lsum) - 0.5f*z*z - logf(s[k]) - HALF_L2PI;
  }
  float cm = comp[0];
#pragma unroll
  for (int k=1;k<KMIX;k++) cm = fmaxf(cm, comp[k]);
  float se = 0.0f;
#pragma unroll
  for (int k=0;k<KMIX;k++) se += expf(comp[k]-cm);
  float nll = -(cm + logf(se));
  // loc L1 vs matched gt
  const float* gb = &s_gt[idx*4];
  float sw = a.z-a.x, sh = a.w-a.y;
  float scx = a.x+0.5f*sw, scy = a.y+0.5f*sh;
  float tw = gb[2]-gb[0], th = gb[3]-gb[1];
  float tcx = gb[0]+0.5f*tw, tcy = gb[1]+0.5f*th;
  float4 d = ((const float4*)deltas)[(size_t)img*R_ANCH + r];
  float loc = fabsf(d.x-(tcx-scx)/sw) + fabsf(d.y-(tcy-scy)/sh)
            + fabsf(d.z-logf(tw/sw)) + fabsf(d.w-logf(th/sh));
  size_t o = (size_t)img*R_ANCH + r;
  label[o] = (signed char)lab; nll_o[o] = nll; loc_o[o] = loc;
  // per-chunk pos/neg counts
  u64 bp = __ballot(lab==1), bn = __ballot(lab==0);
  int wid = tid>>6, lane = tid&63;
  if (lane==0){ s_w[wid*2]=__popcll(bp); s_w[wid*2+1]=__popcll(bn); }
  __syncthreads();
  if (tid==0){
    cpos[img*NCHUNK + blockIdx.x] = s_w[0]+s_w[2]+s_w[4]+s_w[6];
    cneg[img*NCHUNK + blockIdx.x] = s_w[1]+s_w[3]+s_w[5]+s_w[7];
  }
}

// ---------------- L3: per-image chunk-offset scan + quotas ----------------
__global__ void kL3_scan(const int* __restrict__ cpos, const int* __restrict__ cneg,
                         int* __restrict__ opos, int* __restrict__ oneg,
                         int* __restrict__ quota) {
  int img = blockIdx.x;
  if (threadIdx.x == 0){
    int tp=0, tn=0;
    for (int c=0; c<NCHUNK; ++c){
      opos[img*NCHUNK+c]=tp; tp += cpos[img*NCHUNK+c];
      oneg[img*NCHUNK+c]=tn; tn += cneg[img*NCHUNK+c];
    }
    int np = tp < 128 ? tp : 128;
    quota[img*2] = np; quota[img*2+1] = 256 - np;
  }
}

// ---------------- L4: quota-sampled loss accumulation ---------------------
__global__ __launch_bounds__(256) void kL4_accum(
    const signed char* __restrict__ label, const float* __restrict__ nll_i,
    const float* __restrict__ loc_i, const int* __restrict__ opos,
    const int* __restrict__ oneg, const int* __restrict__ quota,
    float* __restrict__ acc) {
  __shared__ int s_wp[4], s_wn[4];
  __shared__ float s_red[8];
  int tid = threadIdx.x, img = blockIdx.y;
  int r = blockIdx.x*256 + tid;
  size_t o = (size_t)img*R_ANCH + r;
  int lab = label[o];
  bool pos = (lab==1), neg = (lab==0);
  u64 bp = __ballot(pos), bn = __ballot(neg);
  int wid = tid>>6, lane = tid&63;
  if (lane==0){ s_wp[wid]=__popcll(bp); s_wn[wid]=__popcll(bn); }
  __syncthreads();
  int pre_p = opos[img*NCHUNK + blockIdx.x];
  int pre_n = oneg[img*NCHUNK + blockIdx.x];
  for (int w=0; w<wid; ++w){ pre_p += s_wp[w]; pre_n += s_wn[w]; }
  u64 lm = (1ull<<lane) - 1ull;
  pre_p += __popcll(bp & lm);
  pre_n += __popcll(bn & lm);
  int np = quota[img*2], nn = quota[img*2+1];
  bool kp = pos && (pre_p < np);
  bool kn = neg && (pre_n < nn);
  float c_cls = (kp||kn) ? nll_i[o] : 0.0f;
  float c_loc = kp ? loc_i[o] : 0.0f;
  for (int of=32; of>0; of>>=1){
    c_cls += __shfl_down(c_cls, of, 64);
    c_loc += __shfl_down(c_loc, of, 64);
  }
  if (lane==0){ s_red[wid]=c_cls; s_red[4+wid]=c_loc; }
  __syncthreads();
  if (tid==0){
    float a = s_red[0]+s_red[1]+s_red[2]+s_red[3];
    float b = s_red[4]+s_red[5]+s_red[6]+s_red[7];
    if (a != 0.0f) atomicAdd(&acc[0], a);
    if (b != 0.0f) atomicAdd(&acc[1], b);
  }
}

// ---------------- F: stable compaction to 1000 + outputs ------------------
__global__ __launch_bounds__(256) void kF_final(
    const float* __restrict__ tb, const float* __restrict__ tu,
    const float* __restrict__ ts, const u64* __restrict__ keepw,
    const float* __restrict__ acc, float* __restrict__ out) {
  __shared__ int s_wk[4], s_wn[4];
  __shared__ int s_kc, s_runk, s_runn;
  int tid = threadIdx.x, img = blockIdx.x;
  int wid = tid>>6, lane = tid&63;
  const u64* kw = keepw + img*32;
  const float NEG_INF = __uint_as_float(0xff800000u);
  // pass 1: total kept (keep bit && non-degenerate after clip)
  int cnt = 0;
  for (int c=0; c<8; ++c){
    int p = c*256 + tid;
    float4 b = ((const float4*)tb)[(size_t)img*PRE + p];
    bool kp = (p < PRE) && (((kw[p>>6]>>(p&63))&1ull)!=0ull) && (b.z > b.x) && (b.w > b.y);
    cnt += kp ? 1 : 0;
  }
  for (int of=32; of>0; of>>=1) cnt += __shfl_down(cnt, of, 64);
  if (lane==0) s_wk[wid] = cnt;
  __syncthreads();
  if (tid==0){ s_kc = s_wk[0]+s_wk[1]+s_wk[2]+s_wk[3]; s_runk=0; s_runn=0; }
  __syncthreads();
  int kc = s_kc;
  // pass 2: stable ranks -> scatter (kept first, then -inf fillers)
  for (int c=0; c<8; ++c){
    int p = c*256 + tid;
    float4 b = ((const float4*)tb)[(size_t)img*PRE + p];
    bool kp = (p < PRE) && (((kw[p>>6]>>(p&63))&1ull)!=0ull) && (b.z > b.x) && (b.w > b.y);
    u64 bk = __ballot(kp), bn = __ballot(!kp);
    if (lane==0){ s_wk[wid]=__popcll(bk); s_wn[wid]=__popcll(bn); }
    __syncthreads();
    int pk = s_runk, pn = s_runn;
    for (int w=0; w<wid; ++w){ pk += s_wk[w]; pn += s_wn[w]; }
    u64 lm = (1ull<<lane) - 1ull;
    pk += __popcll(bk & lm);
    pn += __popcll(bn & lm);
    int slot = kp ? pk : (kc + pn);
    if (slot < POST && p < PRE){
      ((float4*)out)[img*POST + slot] = b;
      out[32000 + img*POST + slot] = kp ? ts[img*PRE + p] : NEG_INF;
      ((float2*)(out + 40000))[img*POST + slot] = ((const float2*)tu)[(size_t)img*PRE + p];
    }
    __syncthreads();
    if (tid==0){
      s_runk += s_wk[0]+s_wk[1]+s_wk[2]+s_wk[3];
      s_runn += s_wn[0]+s_wn[1]+s_wn[2]+s_wn[3];
    }
    __syncthreads();
  }
  if (img==0 && tid<2) out[56000+tid] = acc[tid] * (1.0f/2048.0f);
}

// ---------------- host-side launch ----------------------------------------
extern "C" void kernel_launch(void* const* d_in, const int* in_sizes, int n_in,
                              void* d_out, int out_size, void* d_ws, size_t ws_size,
                              hipStream_t stream) {
  const float* anchors = (const float*)d_in[0];
  const float* pi      = (const float*)d_in[1];
  const float* mu      = (const float*)d_in[2];
  const float* sigma   = (const float*)d_in[3];
  const float* deltas  = (const float*)d_in[4];
  const float* gt      = (const float*)d_in[5];
  float* out = (float*)d_out;

  char* ws = (char*)d_ws;
  size_t off = 0;
  auto alloc = [&](size_t bytes) -> void* {
    void* p = (void*)(ws + off);
    off += (bytes + 255) & ~(size_t)255;
    return p;
  };
  float* logits = (float*)alloc((size_t)NIMG*R_ANCH*4);
  float* epis   = (float*)alloc((size_t)NIMG*R_ANCH*4);
  float* alea   = (float*)alloc((size_t)NIMG*R_ANCH*4);
  float* tb     = (float*)alloc((size_t)NIMG*PRE*4*4);
  float* tu     = (float*)alloc((size_t)NIMG*PRE*2*4);
  float* ts     = (float*)alloc((size_t)NIMG*PRE*4);
  u64*   mask   = (u64*)  alloc((size_t)NIMG*PRE*32*8);
  u64*   keepw  = (u64*)  alloc((size_t)NIMG*32*8);
  int*   best   = (int*)  alloc((size_t)NIMG*NGT*4);
  int*   cpos   = (int*)  alloc((size_t)NIMG*NCHUNK*4);
  int*   cneg   = (int*)  alloc((size_t)NIMG*NCHUNK*4);
  int*   opos   = (int*)  alloc((size_t)NIMG*NCHUNK*4);
  int*   oneg   = (int*)  alloc((size_t)NIMG*NCHUNK*4);
  int*   quota  = (int*)  alloc((size_t)NIMG*2*4);
  float* acc    = (float*)alloc(8);
  // alias dead regions: logits/epis/alea are last read in kB; L2 runs after B.
  signed char* label = (signed char*)logits;
  float* nll = epis;
  float* loc = alea;

  kInit<<<dim3(4), dim3(64), 0, stream>>>(best, acc);
  kA_mdn<<<dim3(NCHUNK, NIMG), dim3(256), 0, stream>>>(pi, mu, sigma, logits, epis, alea);
  kB_topk<<<dim3(NIMG), dim3(1024), 0, stream>>>(logits, epis, alea, deltas, anchors, tb, tu, ts);
  kD_mask<<<dim3(500, NIMG), dim3(256), 0, stream>>>(tb, mask);
  kE_nms<<<dim3(NIMG), dim3(1024), 0, stream>>>(mask, keepw);
  kL1_bestgt<<<dim3(NCHUNK, NIMG), dim3(256), 0, stream>>>(anchors, gt, best);
  kL2_label<<<dim3(NCHUNK, NIMG), dim3(256), 0, stream>>>(anchors, gt, best, pi, mu, sigma,
                                                          deltas, label, nll, loc, cpos, cneg);
  kL3_scan<<<dim3(NIMG), dim3(64), 0, stream>>>(cpos, cneg, opos, oneg, quota);
  kL4_accum<<<dim3(NCHUNK, NIMG), dim3(256), 0, stream>>>(label, nll, loc, opos, oneg, quota, acc);
  kF_final<<<dim3(NIMG), dim3(256), 0, stream>>>(tb, tu, ts, keepw, acc, out);
}

// Round 3
// 548.907 us; speedup vs baseline: 1.6102x; 1.0665x over previous
//
#include <hip/hip_runtime.h>
#include <cstdint>
#include <cstddef>

typedef unsigned long long u64;
typedef unsigned int u32;

#define R_ANCH 96000
#define NIMG   8
#define KMIX   5
#define PRE    2000
#define POST   1000
#define NGT    32
#define NCHUNK 375   // R_ANCH / 256
#define NBLK   48    // blocks per image for grid-stride scan kernels

#define IMG_SZ        1280.0f
#define NMS_T         0.7f
#define SCALE_CLAMP_F 4.135166556742356f
#define HALF_L2PI     0.9189385332046727f

__device__ __forceinline__ u64 make_key(float s, int r) {
  u32 u = __float_as_uint(s);
  u = (u & 0x80000000u) ? ~u : (u | 0x80000000u);
  return ((u64)u << 32) | (u64)(0xFFFFFFFFu - (u32)r);
}

__device__ __forceinline__ float dec_score(u64 key) {
  u32 o = (u32)(key >> 32);
  u32 bits = (o & 0x80000000u) ? (o ^ 0x80000000u) : ~o;
  return __uint_as_float(bits);
}

// contract(off): kL1 and kL2 must produce bit-identical IoU values so that
// "iou >= best_gt - 1e-7" behaves exactly like the reference.
__device__ __forceinline__ float iou_pair(float a0,float a1,float a2,float a3,
                                          float b0,float b1,float b2,float b3) {
#pragma clang fp contract(off)
  float areaA = (a2-a0)*(a3-a1);
  float areaB = (b2-b0)*(b3-b1);
  float lx=fmaxf(a0,b0), ly=fmaxf(a1,b1);
  float rx=fminf(a2,b2), ry=fminf(a3,b3);
  float iw=fmaxf(rx-lx,0.0f), ih=fmaxf(ry-ly,0.0f);
  float inter=iw*ih;
  return inter / fmaxf(areaA+areaB-inter, 1e-9f);
}

__device__ __forceinline__ u64 shfl64(u64 v, int src) {
  int lo = __shfl((int)(u32)v, src, 64);
  int hi = __shfl((int)(u32)(v>>32), src, 64);
  return ((u64)(u32)hi<<32)|(u64)(u32)lo;
}

__device__ __forceinline__ u64 shfl64_xor(u64 v, int m) {
  int lo = __shfl_xor((int)(u32)v, m, 64);
  int hi = __shfl_xor((int)(u32)(v>>32), m, 64);
  return ((u64)(u32)hi<<32)|(u64)(u32)lo;
}

// pick: from a 2048-bin histogram (bin d high = higher keys), find the bin
// containing the k-th largest key. Returns (d, k-within-bin, bin count).
// Must be called by exactly 256 threads. s_i >= 8 ints, s_u >= 3 u32.
__device__ __forceinline__ void pick2048(const u32* __restrict__ hist, int k,
                                         int* s_i, u32* s_u,
                                         int& d_out, int& k_out, u32& cnt_out) {
  int tid = threadIdx.x;
  int lane = tid & 63, w = tid >> 6;
  u32 h[8]; u32 ssum = 0;
#pragma unroll
  for (int i=0;i<8;++i){ h[i] = hist[2047 - (tid*8 + i)]; ssum += h[i]; }
  u32 incl = ssum;
  for (int off=1; off<64; off<<=1){
    u32 t = (u32)__shfl_up((int)incl, off, 64);
    if (lane >= off) incl += t;
  }
  if (lane==63) s_i[w] = (int)incl;
  __syncthreads();
  u32 base = 0;
  for (int ww=0; ww<w; ++ww) base += (u32)s_i[ww];
  u32 run = base + incl - ssum;              // exclusive prefix (descending keys)
#pragma unroll
  for (int i=0;i<8;++i){
    u32 nr = run + h[i];
    if (run < (u32)k && nr >= (u32)k){       // unique crossing thread
      s_u[0] = (u32)(2047 - (tid*8+i));
      s_u[1] = (u32)k - run;
      s_u[2] = h[i];
    }
    run = nr;
  }
  __syncthreads();
  d_out = (int)s_u[0]; k_out = (int)s_u[1]; cnt_out = s_u[2];
  __syncthreads();                           // allow s_u/s_i reuse by caller
}

// ---------------- zero: contiguous workspace region -----------------------
__global__ void kZero(u32* z, int nwords) {
  for (int i = blockIdx.x*256 + threadIdx.x; i < nwords; i += gridDim.x*256)
    z[i] = 0u;
}

// ---------------- A: MDN softmax moments + level-0 histogram --------------
__global__ __launch_bounds__(256) void kA_mdn(
    const float* __restrict__ pi, const float* __restrict__ mu,
    const float* __restrict__ sigma, float* __restrict__ logits,
    float* __restrict__ epis, float* __restrict__ alea,
    u32* __restrict__ hist0) {
  __shared__ u32 s_h[2048];
  int tid = threadIdx.x;
  int r = blockIdx.x*256 + tid;
  int img = blockIdx.y;
  for (int b=tid; b<2048; b+=256) s_h[b]=0u;
  size_t base = (size_t)img*KMIX*R_ANCH + r;
  float p[KMIX], m[KMIX], s[KMIX];
#pragma unroll
  for (int k=0;k<KMIX;k++){
    p[k]=pi[base+(size_t)k*R_ANCH];
    m[k]=mu[base+(size_t)k*R_ANCH];
    s[k]=sigma[base+(size_t)k*R_ANCH];
  }
  float mx = p[0];
#pragma unroll
  for (int k=1;k<KMIX;k++) mx = fmaxf(mx,p[k]);
  float e[KMIX]; float sum = 0.0f;
#pragma unroll
  for (int k=0;k<KMIX;k++){ e[k]=expf(p[k]-mx); sum += e[k]; }
  float w[KMIX]; float lg = 0.0f;
#pragma unroll
  for (int k=0;k<KMIX;k++){ w[k]=e[k]/sum; lg += w[k]*m[k]; }
  float ep = 0.0f, al = 0.0f;
#pragma unroll
  for (int k=0;k<KMIX;k++){ float d=m[k]-lg; ep += w[k]*d*d; al += w[k]*s[k]*s[k]; }
  size_t o = (size_t)img*R_ANCH + r;
  logits[o]=lg; epis[o]=ep; alea[o]=al;
  __syncthreads();                           // s_h zero complete
  u64 key = make_key(lg, r);
  atomicAdd(&s_h[(u32)(key>>53)], 1u);
  __syncthreads();
  for (int b=tid; b<2048; b+=256){ u32 v=s_h[b]; if(v) atomicAdd(&hist0[img*2048+b], v); }
}

// ---------------- P1: refine level-1 histogram (if needed) ----------------
__global__ __launch_bounds__(256) void kP1(const float* __restrict__ logits,
                                           const u32* __restrict__ hist0,
                                           u32* __restrict__ hist1) {
  __shared__ u32 s_h[2048];
  __shared__ int s_i[8]; __shared__ u32 s_u[3];
  int img = blockIdx.y, tid = threadIdx.x;
  int d0,k0; u32 c0;
  pick2048(hist0 + img*2048, PRE, s_i, s_u, d0,k0,c0);
  if (c0 <= 2048u) return;                   // block-uniform
  for (int b=tid; b<2048; b+=256) s_h[b]=0u;
  __syncthreads();
  const float* sc = logits + (size_t)img*R_ANCH;
  for (int r = blockIdx.x*256 + tid; r < R_ANCH; r += NBLK*256){
    u64 key = make_key(sc[r], r);
    if ((int)(key>>53) == d0) atomicAdd(&s_h[(u32)(key>>42)&2047u], 1u);
  }
  __syncthreads();
  for (int b=tid; b<2048; b+=256){ u32 v=s_h[b]; if(v) atomicAdd(&hist1[img*2048+b], v); }
}

// ---------------- P2: refine level-2 histogram (rarely needed) ------------
__global__ __launch_bounds__(256) void kP2(const float* __restrict__ logits,
                                           const u32* __restrict__ hist0,
                                           const u32* __restrict__ hist1,
                                           u32* __restrict__ hist2) {
  __shared__ u32 s_h[2048];
  __shared__ int s_i[8]; __shared__ u32 s_u[3];
  int img = blockIdx.y, tid = threadIdx.x;
  int d0,k0; u32 c0;
  pick2048(hist0 + img*2048, PRE, s_i, s_u, d0,k0,c0);
  if (c0 <= 2048u) return;
  int d1,k1; u32 c1;
  pick2048(hist1 + img*2048, k0, s_i, s_u, d1,k1,c1);
  if (c1 <= 2048u) return;
  u64 p1 = ((u64)d0<<11) | (u64)d1;
  for (int b=tid; b<2048; b+=256) s_h[b]=0u;
  __syncthreads();
  const float* sc = logits + (size_t)img*R_ANCH;
  for (int r = blockIdx.x*256 + tid; r < R_ANCH; r += NBLK*256){
    u64 key = make_key(sc[r], r);
    if ((key>>42) == p1) atomicAdd(&s_h[(u32)(key>>31)&2047u], 1u);
  }
  __syncthreads();
  for (int b=tid; b<2048; b+=256){ u32 v=s_h[b]; if(v) atomicAdd(&hist2[img*2048+b], v); }
}

// ---------------- G: gather candidates >= bin lower bound -----------------
__global__ __launch_bounds__(256) void kGather(const float* __restrict__ logits,
    const u32* __restrict__ hist0, const u32* __restrict__ hist1,
    const u32* __restrict__ hist2, u64* __restrict__ cand, u32* __restrict__ gcnt) {
  __shared__ int s_i[8]; __shared__ u32 s_u[3];
  int img = blockIdx.y, tid = threadIdx.x;
  int d,kk; u32 c;
  pick2048(hist0 + img*2048, PRE, s_i, s_u, d,kk,c);
  u64 p = (u64)d; int L = 0;
  if (c > 2048u){
    pick2048(hist1 + img*2048, kk, s_i, s_u, d,kk,c);
    p = (p<<11)|(u64)d; L = 1;
    if (c > 2048u){
      pick2048(hist2 + img*2048, kk, s_i, s_u, d,kk,c);
      p = (p<<11)|(u64)d; L = 2;
    }
  }
  u64 T = p << (64 - 11*(L+1));              // candidates = (2000-kk)+c <= 4047
  const float* sc = logits + (size_t)img*R_ANCH;
  int lane = tid & 63;
  for (int r = blockIdx.x*256 + tid; r < R_ANCH; r += NBLK*256){
    u64 key = make_key(sc[r], r);
    bool take = (key >= T);
    u64 b = __ballot(take);
    if (b){
      u32 base = 0;
      if (lane==0) base = atomicAdd(&gcnt[img], (u32)__popcll(b));
      base = (u32)__shfl((int)base, 0, 64);
      if (take){
        u32 pos = base + (u32)__popcll(b & ((1ull<<lane)-1ull));
        if (pos < 4096u) cand[(size_t)img*4096 + pos] = key;
      }
    }
  }
}

// ---------------- S: bitonic sort 4096 + exact epilogue -------------------
__global__ __launch_bounds__(1024) void kSort(
    const u64* __restrict__ cand, const u32* __restrict__ gcnt,
    const float* __restrict__ epis, const float* __restrict__ alea,
    const float* __restrict__ deltas, const float* __restrict__ anchors,
    float* __restrict__ tb, float* __restrict__ tu, float* __restrict__ ts) {
  __shared__ u64 s_keys[4096];               // 32 KB
  int tid = threadIdx.x, img = blockIdx.x;
  u32 cnt = gcnt[img];
  if (cnt > 4096u) cnt = 4096u;
  for (int i=tid; i<4096; i+=1024)
    s_keys[i] = (i < (int)cnt) ? cand[(size_t)img*4096 + i] : 0ull;
  __syncthreads();
  for (u32 kk=2; kk<=4096; kk<<=1){
    for (u32 j=kk>>1; j>0; j>>=1){
#pragma unroll
      for (int q0=0; q0<2; ++q0){            // 2048 disjoint pairs / 1024 thr
        u32 q = (u32)tid + (u32)q0*1024u;
        u32 i = ((q & ~(j-1u)) << 1) | (q & (j-1u));
        u32 pi_ = i | j;
        u64 a = s_keys[i], b = s_keys[pi_];
        bool descSeg = ((i & kk) == 0u);
        bool sw = descSeg ? (a < b) : (a > b);
        if (sw){ s_keys[i]=b; s_keys[pi_]=a; }
      }
      __syncthreads();
    }
  }
  for (int p=tid; p<PRE; p+=1024){
    u64 key = s_keys[p];
    u32 idx = 0xFFFFFFFFu - (u32)(key & 0xFFFFFFFFull);
    ts[img*PRE + p] = dec_score(key);
    float4 a = ((const float4*)anchors)[idx];
    float4 d = ((const float4*)deltas)[(size_t)img*R_ANCH + idx];
    float w = a.z - a.x, h = a.w - a.y;
    float cx = a.x + 0.5f*w, cy = a.y + 0.5f*h;
    float dw = fminf(d.z, SCALE_CLAMP_F), dh = fminf(d.w, SCALE_CLAMP_F);
    float pcx = d.x*w + cx, pcy = d.y*h + cy;
    float pw = expf(dw)*w, ph = expf(dh)*h;
    float x0 = fminf(fmaxf(pcx - 0.5f*pw, 0.0f), IMG_SZ);
    float y0 = fminf(fmaxf(pcy - 0.5f*ph, 0.0f), IMG_SZ);
    float x1 = fminf(fmaxf(pcx + 0.5f*pw, 0.0f), IMG_SZ);
    float y1 = fminf(fmaxf(pcy + 0.5f*ph, 0.0f), IMG_SZ);
    ((float4*)tb)[(size_t)img*PRE + p] = make_float4(x0,y0,x1,y1);
    size_t o = (size_t)img*R_ANCH + idx;
    ((float2*)tu)[(size_t)img*PRE + p] = make_float2(epis[o], alea[o]);
  }
}

// ---------------- D: suppression bitmask (upper triangle only) ------------
// kE only ever reads words w >= i>>6 of row i (chain: w==t==i>>6; parallel
// OR: w > t). Words below the diagonal tile are never read -> skip them.
__global__ __launch_bounds__(256) void kD_mask(const float* __restrict__ tb,
                                               u64* __restrict__ mask) {
  __shared__ float4 s_box[PRE];              // 32 KB
  int tid = threadIdx.x, img = blockIdx.y;
  const float4* tbi = (const float4*)tb + (size_t)img*PRE;
  for (int q=tid; q<PRE; q+=256) s_box[q] = tbi[q];
  __syncthreads();
  int wave = tid >> 6, lane = tid & 63;
  int i = blockIdx.x*4 + wave;               // gridDim.x = 500
  float4 A = s_box[i];
  u64* row = mask + ((size_t)img*PRE + i)*32;
  for (int w = i>>6; w<32; ++w){
    int j = w*64 + lane;
    bool bit = false;
    if (j < PRE){
      float4 B = s_box[j];
      float v = iou_pair(A.x,A.y,A.z,A.w, B.x,B.y,B.z,B.w);
      bit = (v > NMS_T) && (j > i);
    }
    u64 m = __ballot(bit);
    if (lane==0) row[w] = m;
  }
}

// ---------------- E: greedy NMS, 16 waves per image -----------------------
__global__ __launch_bounds__(1024) void kE_nms(const u64* __restrict__ mask,
                                               u64* __restrict__ keep) {
  __shared__ u64 s_sup[32];
  __shared__ u64 s_K;
  int img = blockIdx.x;
  int tid = threadIdx.x, wv = tid>>6, lane = tid&63;
  if (tid < 32) s_sup[tid] = 0ull;
  __syncthreads();
  const u64* M = mask + (size_t)img*PRE*32;
  for (int t=0; t<32; ++t){
    int base = t*64;
    int cnt = min(64, PRE - base);
    if (wv == 0){
      u64 myRowT = (lane < cnt) ? M[(size_t)(base+lane)*32 + t] : 0ull;
      u64 nz = __ballot(myRowT != 0ull);
      u64 W = s_sup[t];
      u64 K = 0ull;
      for (int b=0; b<cnt; ++b){
        if (!((W>>b)&1ull)){
          K |= (1ull<<b);
          if ((nz>>b)&1ull) W |= shfl64(myRowT, b);
        }
      }
      if (lane==0){ s_K = K; s_sup[t] = W; }
    }
    __syncthreads();
    u64 K = s_K;
    bool kept = (lane < cnt) && ((K>>lane)&1ull);
    for (int wsel = wv; wsel < 32; wsel += 16){
      if (wsel <= t) continue;
      u64 v = kept ? M[(size_t)(base+lane)*32 + wsel] : 0ull;
      v |= shfl64_xor(v, 1);
      v |= shfl64_xor(v, 2);
      v |= shfl64_xor(v, 4);
      v |= shfl64_xor(v, 8);
      v |= shfl64_xor(v, 16);
      v |= shfl64_xor(v, 32);
      if (lane==0) s_sup[wsel] |= v;
    }
    __syncthreads();
  }
  if (tid < 32) keep[img*32 + tid] = ~s_sup[tid];
}

// ---------------- L1: best IoU per GT over all anchors --------------------
__global__ __launch_bounds__(256) void kL1_bestgt(const float* __restrict__ anchors,
                                                  const float* __restrict__ gt,
                                                  int* __restrict__ best) {
  __shared__ float s_gt[NGT*4];
  __shared__ int s_best[NGT];
  int tid = threadIdx.x, img = blockIdx.y;
  int r = blockIdx.x*256 + tid;
  if (tid < NGT*4) s_gt[tid] = gt[img*NGT*4 + tid];
  if (tid < NGT) s_best[tid] = 0;
  __syncthreads();
  float4 a = ((const float4*)anchors)[r];
#pragma unroll 4
  for (int g=0; g<NGT; ++g){
    float v = iou_pair(s_gt[g*4],s_gt[g*4+1],s_gt[g*4+2],s_gt[g*4+3],
                       a.x,a.y,a.z,a.w);
    if (v > __int_as_float(s_best[g])) atomicMax(&s_best[g], __float_as_int(v));
  }
  __syncthreads();
  if (tid < NGT) atomicMax(&best[img*NGT + tid], s_best[tid]);
}

// ---------------- L2: labels, NLL, L1-loc, per-chunk pos/neg counts -------
__global__ __launch_bounds__(256) void kL2_label(
    const float* __restrict__ anchors, const float* __restrict__ gt,
    const int* __restrict__ best, const float* __restrict__ pi,
    const float* __restrict__ mu, const float* __restrict__ sigma,
    const float* __restrict__ deltas,
    signed char* __restrict__ label, float* __restrict__ nll_o,
    float* __restrict__ loc_o, int* __restrict__ cpos, int* __restrict__ cneg) {
  __shared__ float s_gt[NGT*4];
  __shared__ float s_bg[NGT];
  __shared__ int s_w[8];
  int tid = threadIdx.x, img = blockIdx.y;
  int r = blockIdx.x*256 + tid;
  if (tid < NGT*4) s_gt[tid] = gt[img*NGT*4 + tid];
  if (tid < NGT) s_bg[tid] = __int_as_float(best[img*NGT + tid]);
  __syncthreads();
  float4 a = ((const float4*)anchors)[r];
  float vbest = -1.0f; int idx = 0; bool lq = false;
#pragma unroll 4
  for (int g=0; g<NGT; ++g){
    float v = iou_pair(s_gt[g*4],s_gt[g*4+1],s_gt[g*4+2],s_gt[g*4+3],
                       a.x,a.y,a.z,a.w);
    if (v > vbest){ vbest = v; idx = g; }
    float bg = s_bg[g];
    lq = lq || ((v >= bg - 1e-7f) && (bg > 0.0f));
  }
  int lab = lq ? 1 : (vbest >= 0.7f ? 1 : (vbest >= 0.3f ? -1 : 0));
  size_t base = (size_t)img*KMIX*R_ANCH + r;
  float p[KMIX], m[KMIX], s[KMIX];
#pragma unroll
  for (int k=0;k<KMIX;k++){
    p[k]=pi[base+(size_t)k*R_ANCH];
    m[k]=mu[base+(size_t)k*R_ANCH];
    s[k]=sigma[base+(size_t)k*R_ANCH];
  }
  float mx = p[0];
#pragma unroll
  for (int k=1;k<KMIX;k++) mx = fmaxf(mx,p[k]);
  float sum = 0.0f;
#pragma unroll
  for (int k=0;k<KMIX;k++) sum += expf(p[k]-mx);
  float lsum = logf(sum);
  float t_ = fminf(fmaxf(vbest, 0.0f), 1.0f);
  float comp[KMIX];
#pragma unroll
  for (int k=0;k<KMIX;k++){
    float z = (t_ - m[k]) / s[k];
    comp[k] = (p[k]-mx-lsum) - 0.5f*z*z - logf(s[k]) - HALF_L2PI;
  }
  float cm = comp[0];
#pragma unroll
  for (int k=1;k<KMIX;k++) cm = fmaxf(cm, comp[k]);
  float se = 0.0f;
#pragma unroll
  for (int k=0;k<KMIX;k++) se += expf(comp[k]-cm);
  float nll = -(cm + logf(se));
  const float* gb = &s_gt[idx*4];
  float sw = a.z-a.x, sh = a.w-a.y;
  float scx = a.x+0.5f*sw, scy = a.y+0.5f*sh;
  float tw = gb[2]-gb[0], th = gb[3]-gb[1];
  float tcx = gb[0]+0.5f*tw, tcy = gb[1]+0.5f*th;
  float4 d = ((const float4*)deltas)[(size_t)img*R_ANCH + r];
  float loc = fabsf(d.x-(tcx-scx)/sw) + fabsf(d.y-(tcy-scy)/sh)
            + fabsf(d.z-logf(tw/sw)) + fabsf(d.w-logf(th/sh));
  size_t o = (size_t)img*R_ANCH + r;
  label[o] = (signed char)lab; nll_o[o] = nll; loc_o[o] = loc;
  u64 bp = __ballot(lab==1), bn = __ballot(lab==0);
  int wid = tid>>6, lane = tid&63;
  if (lane==0){ s_w[wid*2]=__popcll(bp); s_w[wid*2+1]=__popcll(bn); }
  __syncthreads();
  if (tid==0){
    cpos[img*NCHUNK + blockIdx.x] = s_w[0]+s_w[2]+s_w[4]+s_w[6];
    cneg[img*NCHUNK + blockIdx.x] = s_w[1]+s_w[3]+s_w[5]+s_w[7];
  }
}

// ---------------- L3: parallel per-image chunk-offset scan + quotas -------
__global__ __launch_bounds__(512) void kL3_scan(const int* __restrict__ cpos,
                                                const int* __restrict__ cneg,
                                                int* __restrict__ opos,
                                                int* __restrict__ oneg,
                                                int* __restrict__ quota) {
  __shared__ int s_p[8], s_n[8];
  int img = blockIdx.x, tid = threadIdx.x;
  int vp=0, vn=0;
  if (tid < NCHUNK){ vp = cpos[img*NCHUNK+tid]; vn = cneg[img*NCHUNK+tid]; }
  int lane = tid&63, w = tid>>6;
  int ip=vp, in_=vn;
  for (int off=1; off<64; off<<=1){
    int tp=__shfl_up(ip,off,64), tn=__shfl_up(in_,off,64);
    if (lane>=off){ ip+=tp; in_+=tn; }
  }
  if (lane==63){ s_p[w]=ip; s_n[w]=in_; }
  __syncthreads();
  int bp=0,bn=0;
  for (int ww=0; ww<w; ++ww){ bp+=s_p[ww]; bn+=s_n[ww]; }
  if (tid < NCHUNK){
    opos[img*NCHUNK+tid] = bp+ip-vp;
    oneg[img*NCHUNK+tid] = bn+in_-vn;
  }
  if (tid==0){
    int tp=0,tn=0;
    for (int ww=0; ww<8; ++ww){ tp+=s_p[ww]; tn+=s_n[ww]; }
    int np = tp<128?tp:128;
    quota[img*2]=np; quota[img*2+1]=256-np;
  }
}

// ---------------- L4: quota-sampled loss accumulation ---------------------
__global__ __launch_bounds__(256) void kL4_accum(
    const signed char* __restrict__ label, const float* __restrict__ nll_i,
    const float* __restrict__ loc_i, const int* __restrict__ opos,
    const int* __restrict__ oneg, const int* __restrict__ quota,
    float* __restrict__ acc) {
  __shared__ int s_wp[4], s_wn[4];
  __shared__ float s_red[8];
  int tid = threadIdx.x, img = blockIdx.y;
  int r = blockIdx.x*256 + tid;
  size_t o = (size_t)img*R_ANCH + r;
  int lab = label[o];
  bool pos = (lab==1), neg = (lab==0);
  u64 bp = __ballot(pos), bn = __ballot(neg);
  int wid = tid>>6, lane = tid&63;
  if (lane==0){ s_wp[wid]=__popcll(bp); s_wn[wid]=__popcll(bn); }
  __syncthreads();
  int pre_p = opos[img*NCHUNK + blockIdx.x];
  int pre_n = oneg[img*NCHUNK + blockIdx.x];
  for (int w=0; w<wid; ++w){ pre_p += s_wp[w]; pre_n += s_wn[w]; }
  u64 lm = (1ull<<lane) - 1ull;
  pre_p += __popcll(bp & lm);
  pre_n += __popcll(bn & lm);
  int np = quota[img*2], nn = quota[img*2+1];
  bool kp = pos && (pre_p < np);
  bool kn = neg && (pre_n < nn);
  float c_cls = (kp||kn) ? nll_i[o] : 0.0f;
  float c_loc = kp ? loc_i[o] : 0.0f;
  for (int of=32; of>0; of>>=1){
    c_cls += __shfl_down(c_cls, of, 64);
    c_loc += __shfl_down(c_loc, of, 64);
  }
  if (lane==0){ s_red[wid]=c_cls; s_red[4+wid]=c_loc; }
  __syncthreads();
  if (tid==0){
    float a = s_red[0]+s_red[1]+s_red[2]+s_red[3];
    float b = s_red[4]+s_red[5]+s_red[6]+s_red[7];
    if (a != 0.0f) atomicAdd(&acc[0], a);
    if (b != 0.0f) atomicAdd(&acc[1], b);
  }
}

// ---------------- F: stable compaction to 1000 + outputs ------------------
__global__ __launch_bounds__(256) void kF_final(
    const float* __restrict__ tb, const float* __restrict__ tu,
    const float* __restrict__ ts, const u64* __restrict__ keepw,
    const float* __restrict__ acc, float* __restrict__ out) {
  __shared__ int s_wk[4], s_wn[4];
  __shared__ int s_kc, s_runk, s_runn;
  int tid = threadIdx.x, img = blockIdx.x;
  int wid = tid>>6, lane = tid&63;
  const u64* kw = keepw + img*32;
  const float NEG_INF = __uint_as_float(0xff800000u);
  int cnt = 0;
  for (int c=0; c<8; ++c){
    int p = c*256 + tid;
    float4 b = ((const float4*)tb)[(size_t)img*PRE + p];
    bool kp = (p < PRE) && (((kw[p>>6]>>(p&63))&1ull)!=0ull) && (b.z > b.x) && (b.w > b.y);
    cnt += kp ? 1 : 0;
  }
  for (int of=32; of>0; of>>=1) cnt += __shfl_down(cnt, of, 64);
  if (lane==0) s_wk[wid] = cnt;
  __syncthreads();
  if (tid==0){ s_kc = s_wk[0]+s_wk[1]+s_wk[2]+s_wk[3]; s_runk=0; s_runn=0; }
  __syncthreads();
  int kc = s_kc;
  for (int c=0; c<8; ++c){
    int p = c*256 + tid;
    float4 b = ((const float4*)tb)[(size_t)img*PRE + p];
    bool kp = (p < PRE) && (((kw[p>>6]>>(p&63))&1ull)!=0ull) && (b.z > b.x) && (b.w > b.y);
    u64 bk = __ballot(kp), bn = __ballot(!kp);
    if (lane==0){ s_wk[wid]=__popcll(bk); s_wn[wid]=__popcll(bn); }
    __syncthreads();
    int pk = s_runk, pn = s_runn;
    for (int w=0; w<wid; ++w){ pk += s_wk[w]; pn += s_wn[w]; }
    u64 lm = (1ull<<lane) - 1ull;
    pk += __popcll(bk & lm);
    pn += __popcll(bn & lm);
    int slot = kp ? pk : (kc + pn);
    if (slot < POST && p < PRE){
      ((float4*)out)[img*POST + slot] = b;
      out[32000 + img*POST + slot] = kp ? ts[img*PRE + p] : NEG_INF;
      ((float2*)(out + 40000))[img*POST + slot] = ((const float2*)tu)[(size_t)img*PRE + p];
    }
    __syncthreads();
    if (tid==0){
      s_runk += s_wk[0]+s_wk[1]+s_wk[2]+s_wk[3];
      s_runn += s_wn[0]+s_wn[1]+s_wn[2]+s_wn[3];
    }
    __syncthreads();
  }
  if (img==0 && tid<2) out[56000+tid] = acc[tid] * (1.0f/2048.0f);
}

// ---------------- host-side launch ----------------------------------------
extern "C" void kernel_launch(void* const* d_in, const int* in_sizes, int n_in,
                              void* d_out, int out_size, void* d_ws, size_t ws_size,
                              hipStream_t stream) {
  const float* anchors = (const float*)d_in[0];
  const float* pi      = (const float*)d_in[1];
  const float* mu      = (const float*)d_in[2];
  const float* sigma   = (const float*)d_in[3];
  const float* deltas  = (const float*)d_in[4];
  const float* gt      = (const float*)d_in[5];
  float* out = (float*)d_out;

  char* ws = (char*)d_ws;
  size_t off = 0;
  auto alloc = [&](size_t bytes) -> void* {
    void* p = (void*)(ws + off);
    off += (bytes + 255) & ~(size_t)255;
    return p;
  };
  float* logits = (float*)alloc((size_t)NIMG*R_ANCH*4);
  float* epis   = (float*)alloc((size_t)NIMG*R_ANCH*4);
  float* alea   = (float*)alloc((size_t)NIMG*R_ANCH*4);
  float* tb     = (float*)alloc((size_t)NIMG*PRE*4*4);
  float* tu     = (float*)alloc((size_t)NIMG*PRE*2*4);
  float* ts     = (float*)alloc((size_t)NIMG*PRE*4);
  u64*   mask   = (u64*)  alloc((size_t)NIMG*PRE*32*8);
  u64*   keepw  = (u64*)  alloc((size_t)NIMG*32*8);
  u64*   cand   = (u64*)  alloc((size_t)NIMG*4096*8);
  int*   cpos   = (int*)  alloc((size_t)NIMG*NCHUNK*4);
  int*   cneg   = (int*)  alloc((size_t)NIMG*NCHUNK*4);
  int*   opos   = (int*)  alloc((size_t)NIMG*NCHUNK*4);
  int*   oneg   = (int*)  alloc((size_t)NIMG*NCHUNK*4);
  int*   quota  = (int*)  alloc((size_t)NIMG*2*4);
  // ---- contiguous zero region (hist0..acc) ----
  size_t zstart = off;
  u32*   hist0  = (u32*)  alloc((size_t)NIMG*2048*4);
  u32*   hist1  = (u32*)  alloc((size_t)NIMG*2048*4);
  u32*   hist2  = (u32*)  alloc((size_t)NIMG*2048*4);
  u32*   gcnt   = (u32*)  alloc((size_t)NIMG*4);
  int*   best   = (int*)  alloc((size_t)NIMG*NGT*4);
  float* acc    = (float*)alloc(8);
  int zwords = (int)((off - zstart) / 4);
  // alias dead regions: logits/epis/alea last read in kSort; L2 runs after.
  signed char* label = (signed char*)logits;
  float* nll = epis;
  float* loc = alea;

  kZero<<<dim3(64), dim3(256), 0, stream>>>((u32*)(ws + zstart), zwords);
  kA_mdn<<<dim3(NCHUNK, NIMG), dim3(256), 0, stream>>>(pi, mu, sigma, logits, epis, alea, hist0);
  kP1<<<dim3(NBLK, NIMG), dim3(256), 0, stream>>>(logits, hist0, hist1);
  kP2<<<dim3(NBLK, NIMG), dim3(256), 0, stream>>>(logits, hist0, hist1, hist2);
  kGather<<<dim3(NBLK, NIMG), dim3(256), 0, stream>>>(logits, hist0, hist1, hist2, cand, gcnt);
  kSort<<<dim3(NIMG), dim3(1024), 0, stream>>>(cand, gcnt, epis, alea, deltas, anchors, tb, tu, ts);
  kD_mask<<<dim3(500, NIMG), dim3(256), 0, stream>>>(tb, mask);
  kE_nms<<<dim3(NIMG), dim3(1024), 0, stream>>>(mask, keepw);
  kL1_bestgt<<<dim3(NCHUNK, NIMG), dim3(256), 0, stream>>>(anchors, gt, best);
  kL2_label<<<dim3(NCHUNK, NIMG), dim3(256), 0, stream>>>(anchors, gt, best, pi, mu, sigma,
                                                          deltas, label, nll, loc, cpos, cneg);
  kL3_scan<<<dim3(NIMG), dim3(512), 0, stream>>>(cpos, cneg, opos, oneg, quota);
  kL4_accum<<<dim3(NCHUNK, NIMG), dim3(256), 0, stream>>>(label, nll, loc, opos, oneg, quota, acc);
  kF_final<<<dim3(NIMG), dim3(256), 0, stream>>>(tb, tu, ts, keepw, acc, out);
}

// Round 4
// 546.656 us; speedup vs baseline: 1.6168x; 1.0041x over previous
//
#include <hip/hip_runtime.h>
#include <cstdint>
#include <cstddef>

typedef unsigned long long u64;
typedef unsigned int u32;

#define R_ANCH 96000
#define NIMG   8
#define KMIX   5
#define PRE    2000
#define POST   1000
#define NGT    32
#define NCHUNK 375   // R_ANCH / 256
#define NBLK   48    // blocks per image for grid-stride scan kernels
#define MROW   2048  // transposed-mask row stride (padded PRE)

#define IMG_SZ        1280.0f
#define NMS_T         0.7f
#define SCALE_CLAMP_F 4.135166556742356f
#define HALF_L2PI     0.9189385332046727f

__device__ __forceinline__ u64 make_key(float s, int r) {
  u32 u = __float_as_uint(s);
  u = (u & 0x80000000u) ? ~u : (u | 0x80000000u);
  return ((u64)u << 32) | (u64)(0xFFFFFFFFu - (u32)r);
}

__device__ __forceinline__ float dec_score(u64 key) {
  u32 o = (u32)(key >> 32);
  u32 bits = (o & 0x80000000u) ? (o ^ 0x80000000u) : ~o;
  return __uint_as_float(bits);
}

// contract(off): kL1 and kL2 must produce bit-identical IoU values so that
// "iou >= best_gt - 1e-7" behaves exactly like the reference.
__device__ __forceinline__ float iou_pair(float a0,float a1,float a2,float a3,
                                          float b0,float b1,float b2,float b3) {
#pragma clang fp contract(off)
  float areaA = (a2-a0)*(a3-a1);
  float areaB = (b2-b0)*(b3-b1);
  float lx=fmaxf(a0,b0), ly=fmaxf(a1,b1);
  float rx=fminf(a2,b2), ry=fminf(a3,b3);
  float iw=fmaxf(rx-lx,0.0f), ih=fmaxf(ry-ly,0.0f);
  float inter=iw*ih;
  return inter / fmaxf(areaA+areaB-inter, 1e-9f);
}

__device__ __forceinline__ u64 shfl64(u64 v, int src) {
  int lo = __shfl((int)(u32)v, src, 64);
  int hi = __shfl((int)(u32)(v>>32), src, 64);
  return ((u64)(u32)hi<<32)|(u64)(u32)lo;
}

__device__ __forceinline__ u64 shfl64_xor(u64 v, int m) {
  int lo = __shfl_xor((int)(u32)v, m, 64);
  int hi = __shfl_xor((int)(u32)(v>>32), m, 64);
  return ((u64)(u32)hi<<32)|(u64)(u32)lo;
}

// pick: from a 2048-bin histogram (bin d high = higher keys), find the bin
// containing the k-th largest key. Returns (d, k-within-bin, bin count).
// Must be called by exactly 256 threads. s_i >= 8 ints, s_u >= 3 u32.
__device__ __forceinline__ void pick2048(const u32* __restrict__ hist, int k,
                                         int* s_i, u32* s_u,
                                         int& d_out, int& k_out, u32& cnt_out) {
  int tid = threadIdx.x;
  int lane = tid & 63, w = tid >> 6;
  u32 h[8]; u32 ssum = 0;
#pragma unroll
  for (int i=0;i<8;++i){ h[i] = hist[2047 - (tid*8 + i)]; ssum += h[i]; }
  u32 incl = ssum;
  for (int off=1; off<64; off<<=1){
    u32 t = (u32)__shfl_up((int)incl, off, 64);
    if (lane >= off) incl += t;
  }
  if (lane==63) s_i[w] = (int)incl;
  __syncthreads();
  u32 base = 0;
  for (int ww=0; ww<w; ++ww) base += (u32)s_i[ww];
  u32 run = base + incl - ssum;              // exclusive prefix (descending keys)
#pragma unroll
  for (int i=0;i<8;++i){
    u32 nr = run + h[i];
    if (run < (u32)k && nr >= (u32)k){       // unique crossing thread
      s_u[0] = (u32)(2047 - (tid*8+i));
      s_u[1] = (u32)k - run;
      s_u[2] = h[i];
    }
    run = nr;
  }
  __syncthreads();
  d_out = (int)s_u[0]; k_out = (int)s_u[1]; cnt_out = s_u[2];
  __syncthreads();                           // allow s_u/s_i reuse by caller
}

// ---------------- zero: contiguous workspace region -----------------------
__global__ void kZero(u32* z, int nwords) {
  for (int i = blockIdx.x*256 + threadIdx.x; i < nwords; i += gridDim.x*256)
    z[i] = 0u;
}

// ---------------- A: MDN softmax moments + level-0 histogram --------------
__global__ __launch_bounds__(256) void kA_mdn(
    const float* __restrict__ pi, const float* __restrict__ mu,
    const float* __restrict__ sigma, float* __restrict__ logits,
    float* __restrict__ epis, float* __restrict__ alea,
    u32* __restrict__ hist0) {
  __shared__ u32 s_h[2048];
  int tid = threadIdx.x;
  int r = blockIdx.x*256 + tid;
  int img = blockIdx.y;
  for (int b=tid; b<2048; b+=256) s_h[b]=0u;
  size_t base = (size_t)img*KMIX*R_ANCH + r;
  float p[KMIX], m[KMIX], s[KMIX];
#pragma unroll
  for (int k=0;k<KMIX;k++){
    p[k]=pi[base+(size_t)k*R_ANCH];
    m[k]=mu[base+(size_t)k*R_ANCH];
    s[k]=sigma[base+(size_t)k*R_ANCH];
  }
  float mx = p[0];
#pragma unroll
  for (int k=1;k<KMIX;k++) mx = fmaxf(mx,p[k]);
  float e[KMIX]; float sum = 0.0f;
#pragma unroll
  for (int k=0;k<KMIX;k++){ e[k]=expf(p[k]-mx); sum += e[k]; }
  float w[KMIX]; float lg = 0.0f;
#pragma unroll
  for (int k=0;k<KMIX;k++){ w[k]=e[k]/sum; lg += w[k]*m[k]; }
  float ep = 0.0f, al = 0.0f;
#pragma unroll
  for (int k=0;k<KMIX;k++){ float d=m[k]-lg; ep += w[k]*d*d; al += w[k]*s[k]*s[k]; }
  size_t o = (size_t)img*R_ANCH + r;
  logits[o]=lg; epis[o]=ep; alea[o]=al;
  __syncthreads();                           // s_h zero complete
  u64 key = make_key(lg, r);
  atomicAdd(&s_h[(u32)(key>>53)], 1u);
  __syncthreads();
  for (int b=tid; b<2048; b+=256){ u32 v=s_h[b]; if(v) atomicAdd(&hist0[img*2048+b], v); }
}

// ---------------- P1: refine level-1 histogram (if needed) ----------------
__global__ __launch_bounds__(256) void kP1(const float* __restrict__ logits,
                                           const u32* __restrict__ hist0,
                                           u32* __restrict__ hist1) {
  __shared__ u32 s_h[2048];
  __shared__ int s_i[8]; __shared__ u32 s_u[3];
  int img = blockIdx.y, tid = threadIdx.x;
  int d0,k0; u32 c0;
  pick2048(hist0 + img*2048, PRE, s_i, s_u, d0,k0,c0);
  if (c0 <= 2048u) return;                   // block-uniform
  for (int b=tid; b<2048; b+=256) s_h[b]=0u;
  __syncthreads();
  const float* sc = logits + (size_t)img*R_ANCH;
  for (int r = blockIdx.x*256 + tid; r < R_ANCH; r += NBLK*256){
    u64 key = make_key(sc[r], r);
    if ((int)(key>>53) == d0) atomicAdd(&s_h[(u32)(key>>42)&2047u], 1u);
  }
  __syncthreads();
  for (int b=tid; b<2048; b+=256){ u32 v=s_h[b]; if(v) atomicAdd(&hist1[img*2048+b], v); }
}

// ---------------- P2: refine level-2 histogram (rarely needed) ------------
__global__ __launch_bounds__(256) void kP2(const float* __restrict__ logits,
                                           const u32* __restrict__ hist0,
                                           const u32* __restrict__ hist1,
                                           u32* __restrict__ hist2) {
  __shared__ u32 s_h[2048];
  __shared__ int s_i[8]; __shared__ u32 s_u[3];
  int img = blockIdx.y, tid = threadIdx.x;
  int d0,k0; u32 c0;
  pick2048(hist0 + img*2048, PRE, s_i, s_u, d0,k0,c0);
  if (c0 <= 2048u) return;
  int d1,k1; u32 c1;
  pick2048(hist1 + img*2048, k0, s_i, s_u, d1,k1,c1);
  if (c1 <= 2048u) return;
  u64 p1 = ((u64)d0<<11) | (u64)d1;
  for (int b=tid; b<2048; b+=256) s_h[b]=0u;
  __syncthreads();
  const float* sc = logits + (size_t)img*R_ANCH;
  for (int r = blockIdx.x*256 + tid; r < R_ANCH; r += NBLK*256){
    u64 key = make_key(sc[r], r);
    if ((key>>42) == p1) atomicAdd(&s_h[(u32)(key>>31)&2047u], 1u);
  }
  __syncthreads();
  for (int b=tid; b<2048; b+=256){ u32 v=s_h[b]; if(v) atomicAdd(&hist2[img*2048+b], v); }
}

// ---------------- G: gather candidates >= bin lower bound -----------------
__global__ __launch_bounds__(256) void kGather(const float* __restrict__ logits,
    const u32* __restrict__ hist0, const u32* __restrict__ hist1,
    const u32* __restrict__ hist2, u64* __restrict__ cand, u32* __restrict__ gcnt) {
  __shared__ int s_i[8]; __shared__ u32 s_u[3];
  int img = blockIdx.y, tid = threadIdx.x;
  int d,kk; u32 c;
  pick2048(hist0 + img*2048, PRE, s_i, s_u, d,kk,c);
  u64 p = (u64)d; int L = 0;
  if (c > 2048u){
    pick2048(hist1 + img*2048, kk, s_i, s_u, d,kk,c);
    p = (p<<11)|(u64)d; L = 1;
    if (c > 2048u){
      pick2048(hist2 + img*2048, kk, s_i, s_u, d,kk,c);
      p = (p<<11)|(u64)d; L = 2;
    }
  }
  u64 T = p << (64 - 11*(L+1));              // candidates = (2000-kk)+c <= 4047
  const float* sc = logits + (size_t)img*R_ANCH;
  int lane = tid & 63;
  for (int r = blockIdx.x*256 + tid; r < R_ANCH; r += NBLK*256){
    u64 key = make_key(sc[r], r);
    bool take = (key >= T);
    u64 b = __ballot(take);
    if (b){
      u32 base = 0;
      if (lane==0) base = atomicAdd(&gcnt[img], (u32)__popcll(b));
      base = (u32)__shfl((int)base, 0, 64);
      if (take){
        u32 pos = base + (u32)__popcll(b & ((1ull<<lane)-1ull));
        if (pos < 4096u) cand[(size_t)img*4096 + pos] = key;
      }
    }
  }
}

// ---------------- S: bitonic sort 4096 + exact epilogue -------------------
__global__ __launch_bounds__(1024) void kSort(
    const u64* __restrict__ cand, const u32* __restrict__ gcnt,
    const float* __restrict__ epis, const float* __restrict__ alea,
    const float* __restrict__ deltas, const float* __restrict__ anchors,
    float* __restrict__ tb, float* __restrict__ tu, float* __restrict__ ts) {
  __shared__ u64 s_keys[4096];               // 32 KB
  int tid = threadIdx.x, img = blockIdx.x;
  u32 cnt = gcnt[img];
  if (cnt > 4096u) cnt = 4096u;
  for (int i=tid; i<4096; i+=1024)
    s_keys[i] = (i < (int)cnt) ? cand[(size_t)img*4096 + i] : 0ull;
  __syncthreads();
  for (u32 kk=2; kk<=4096; kk<<=1){
    for (u32 j=kk>>1; j>0; j>>=1){
#pragma unroll
      for (int q0=0; q0<2; ++q0){            // 2048 disjoint pairs / 1024 thr
        u32 q = (u32)tid + (u32)q0*1024u;
        u32 i = ((q & ~(j-1u)) << 1) | (q & (j-1u));
        u32 pi_ = i | j;
        u64 a = s_keys[i], b = s_keys[pi_];
        bool descSeg = ((i & kk) == 0u);
        bool sw = descSeg ? (a < b) : (a > b);
        if (sw){ s_keys[i]=b; s_keys[pi_]=a; }
      }
      __syncthreads();
    }
  }
  for (int p=tid; p<PRE; p+=1024){
    u64 key = s_keys[p];
    u32 idx = 0xFFFFFFFFu - (u32)(key & 0xFFFFFFFFull);
    ts[img*PRE + p] = dec_score(key);
    float4 a = ((const float4*)anchors)[idx];
    float4 d = ((const float4*)deltas)[(size_t)img*R_ANCH + idx];
    float w = a.z - a.x, h = a.w - a.y;
    float cx = a.x + 0.5f*w, cy = a.y + 0.5f*h;
    float dw = fminf(d.z, SCALE_CLAMP_F), dh = fminf(d.w, SCALE_CLAMP_F);
    float pcx = d.x*w + cx, pcy = d.y*h + cy;
    float pw = expf(dw)*w, ph = expf(dh)*h;
    float x0 = fminf(fmaxf(pcx - 0.5f*pw, 0.0f), IMG_SZ);
    float y0 = fminf(fmaxf(pcy - 0.5f*ph, 0.0f), IMG_SZ);
    float x1 = fminf(fmaxf(pcx + 0.5f*pw, 0.0f), IMG_SZ);
    float y1 = fminf(fmaxf(pcy + 0.5f*ph, 0.0f), IMG_SZ);
    ((float4*)tb)[(size_t)img*PRE + p] = make_float4(x0,y0,x1,y1);
    size_t o = (size_t)img*R_ANCH + idx;
    ((float2*)tu)[(size_t)img*PRE + p] = make_float2(epis[o], alea[o]);
  }
}

// ---------------- D: suppression bitmask, TRANSPOSED layout ---------------
// maskT[img][word][row]: row-stride 1 so kE's per-word loads over 64
// consecutive rows are coalesced (8 cache lines vs 64 with row-major).
// kE only reads words w >= i>>6 of row i -> skip lower-triangle words.
__global__ __launch_bounds__(256) void kD_mask(const float* __restrict__ tb,
                                               u64* __restrict__ maskT) {
  __shared__ float4 s_box[PRE];              // 32 KB
  int tid = threadIdx.x, img = blockIdx.y;
  const float4* tbi = (const float4*)tb + (size_t)img*PRE;
  for (int q=tid; q<PRE; q+=256) s_box[q] = tbi[q];
  __syncthreads();
  int wave = tid >> 6, lane = tid & 63;
  int i = blockIdx.x*4 + wave;               // gridDim.x = 500
  float4 A = s_box[i];
  u64* MT = maskT + (size_t)img*32*MROW;
  for (int w = i>>6; w<32; ++w){
    int j = w*64 + lane;
    bool bit = false;
    if (j < PRE){
      float4 B = s_box[j];
      float v = iou_pair(A.x,A.y,A.z,A.w, B.x,B.y,B.z,B.w);
      bit = (v > NMS_T) && (j > i);
    }
    u64 m = __ballot(bit);
    if (lane==0) MT[(size_t)w*MROW + i] = m;
  }
}

// ---------------- E: greedy NMS, 16 waves per image, coalesced ------------
__global__ __launch_bounds__(1024) void kE_nms(const u64* __restrict__ maskT,
                                               u64* __restrict__ keep) {
  __shared__ u64 s_sup[32];
  __shared__ u64 s_K;
  int img = blockIdx.x;
  int tid = threadIdx.x, wv = tid>>6, lane = tid&63;
  if (tid < 32) s_sup[tid] = 0ull;
  __syncthreads();
  const u64* MT = maskT + (size_t)img*32*MROW;
  for (int t=0; t<32; ++t){
    int base = t*64;
    int cnt = min(64, PRE - base);           // last tile: 16
    if (wv == 0){
      u64 myRowT = (lane < cnt) ? MT[(size_t)t*MROW + base + lane] : 0ull;
      u64 nz = __ballot(myRowT != 0ull);
      u64 W = s_sup[t];                      // wave-uniform
      u64 valid = (cnt==64) ? ~0ull : ((1ull<<cnt)-1ull);
      u64 live = ~W & valid;
      u64 K = 0ull;
      while (live){                          // wave-uniform; iterates kept bits
        int b = __builtin_ctzll(live);
        K |= (1ull<<b);
        live &= live - 1ull;                 // clear bit b
        if ((nz>>b)&1ull){
          u64 rb = shfl64(myRowT, b);        // only bits > b set
          W |= rb;
          live &= ~rb;
        }
      }
      if (lane==0){ s_K = K; s_sup[t] = W; } // W = final word t
    }
    __syncthreads();
    u64 K = s_K;
    bool kept = (lane < cnt) && ((K>>lane)&1ull);
    for (int wsel = wv; wsel < 32; wsel += 16){
      if (wsel <= t) continue;               // words <= t already finalized
      u64 v = kept ? MT[(size_t)wsel*MROW + base + lane] : 0ull;
      if (__ballot(v != 0ull)){              // sparse: usually all-zero
        v |= shfl64_xor(v, 1);
        v |= shfl64_xor(v, 2);
        v |= shfl64_xor(v, 4);
        v |= shfl64_xor(v, 8);
        v |= shfl64_xor(v, 16);
        v |= shfl64_xor(v, 32);
        if (lane==0) s_sup[wsel] |= v;       // single writer per word
      }
    }
    __syncthreads();
  }
  if (tid < 32) keep[img*32 + tid] = ~s_sup[tid];
}

// ---------------- L1: best IoU per GT over all anchors --------------------
__global__ __launch_bounds__(256) void kL1_bestgt(const float* __restrict__ anchors,
                                                  const float* __restrict__ gt,
                                                  int* __restrict__ best) {
  __shared__ float s_gt[NGT*4];
  __shared__ int s_best[NGT];
  int tid = threadIdx.x, img = blockIdx.y;
  int r = blockIdx.x*256 + tid;
  if (tid < NGT*4) s_gt[tid] = gt[img*NGT*4 + tid];
  if (tid < NGT) s_best[tid] = 0;
  __syncthreads();
  float4 a = ((const float4*)anchors)[r];
#pragma unroll 4
  for (int g=0; g<NGT; ++g){
    float v = iou_pair(s_gt[g*4],s_gt[g*4+1],s_gt[g*4+2],s_gt[g*4+3],
                       a.x,a.y,a.z,a.w);
    if (v > __int_as_float(s_best[g])) atomicMax(&s_best[g], __float_as_int(v));
  }
  __syncthreads();
  if (tid < NGT) atomicMax(&best[img*NGT + tid], s_best[tid]);
}

// ---------------- L2: labels, NLL, L1-loc, per-chunk pos/neg counts -------
__global__ __launch_bounds__(256) void kL2_label(
    const float* __restrict__ anchors, const float* __restrict__ gt,
    const int* __restrict__ best, const float* __restrict__ pi,
    const float* __restrict__ mu, const float* __restrict__ sigma,
    const float* __restrict__ deltas,
    signed char* __restrict__ label, float* __restrict__ nll_o,
    float* __restrict__ loc_o, int* __restrict__ cpos, int* __restrict__ cneg) {
  __shared__ float s_gt[NGT*4];
  __shared__ float s_bg[NGT];
  __shared__ int s_w[8];
  int tid = threadIdx.x, img = blockIdx.y;
  int r = blockIdx.x*256 + tid;
  if (tid < NGT*4) s_gt[tid] = gt[img*NGT*4 + tid];
  if (tid < NGT) s_bg[tid] = __int_as_float(best[img*NGT + tid]);
  __syncthreads();
  float4 a = ((const float4*)anchors)[r];
  float vbest = -1.0f; int idx = 0; bool lq = false;
#pragma unroll 4
  for (int g=0; g<NGT; ++g){
    float v = iou_pair(s_gt[g*4],s_gt[g*4+1],s_gt[g*4+2],s_gt[g*4+3],
                       a.x,a.y,a.z,a.w);
    if (v > vbest){ vbest = v; idx = g; }
    float bg = s_bg[g];
    lq = lq || ((v >= bg - 1e-7f) && (bg > 0.0f));
  }
  int lab = lq ? 1 : (vbest >= 0.7f ? 1 : (vbest >= 0.3f ? -1 : 0));
  size_t base = (size_t)img*KMIX*R_ANCH + r;
  float p[KMIX], m[KMIX], s[KMIX];
#pragma unroll
  for (int k=0;k<KMIX;k++){
    p[k]=pi[base+(size_t)k*R_ANCH];
    m[k]=mu[base+(size_t)k*R_ANCH];
    s[k]=sigma[base+(size_t)k*R_ANCH];
  }
  float mx = p[0];
#pragma unroll
  for (int k=1;k<KMIX;k++) mx = fmaxf(mx,p[k]);
  float sum = 0.0f;
#pragma unroll
  for (int k=0;k<KMIX;k++) sum += expf(p[k]-mx);
  float lsum = logf(sum);
  float t_ = fminf(fmaxf(vbest, 0.0f), 1.0f);
  float comp[KMIX];
#pragma unroll
  for (int k=0;k<KMIX;k++){
    float z = (t_ - m[k]) / s[k];
    comp[k] = (p[k]-mx-lsum) - 0.5f*z*z - logf(s[k]) - HALF_L2PI;
  }
  float cm = comp[0];
#pragma unroll
  for (int k=1;k<KMIX;k++) cm = fmaxf(cm, comp[k]);
  float se = 0.0f;
#pragma unroll
  for (int k=0;k<KMIX;k++) se += expf(comp[k]-cm);
  float nll = -(cm + logf(se));
  const float* gb = &s_gt[idx*4];
  float sw = a.z-a.x, sh = a.w-a.y;
  float scx = a.x+0.5f*sw, scy = a.y+0.5f*sh;
  float tw = gb[2]-gb[0], th = gb[3]-gb[1];
  float tcx = gb[0]+0.5f*tw, tcy = gb[1]+0.5f*th;
  float4 d = ((const float4*)deltas)[(size_t)img*R_ANCH + r];
  float loc = fabsf(d.x-(tcx-scx)/sw) + fabsf(d.y-(tcy-scy)/sh)
            + fabsf(d.z-logf(tw/sw)) + fabsf(d.w-logf(th/sh));
  size_t o = (size_t)img*R_ANCH + r;
  label[o] = (signed char)lab; nll_o[o] = nll; loc_o[o] = loc;
  u64 bp = __ballot(lab==1), bn = __ballot(lab==0);
  int wid = tid>>6, lane = tid&63;
  if (lane==0){ s_w[wid*2]=__popcll(bp); s_w[wid*2+1]=__popcll(bn); }
  __syncthreads();
  if (tid==0){
    cpos[img*NCHUNK + blockIdx.x] = s_w[0]+s_w[2]+s_w[4]+s_w[6];
    cneg[img*NCHUNK + blockIdx.x] = s_w[1]+s_w[3]+s_w[5]+s_w[7];
  }
}

// ---------------- L3: parallel per-image chunk-offset scan + quotas -------
__global__ __launch_bounds__(512) void kL3_scan(const int* __restrict__ cpos,
                                                const int* __restrict__ cneg,
                                                int* __restrict__ opos,
                                                int* __restrict__ oneg,
                                                int* __restrict__ quota) {
  __shared__ int s_p[8], s_n[8];
  int img = blockIdx.x, tid = threadIdx.x;
  int vp=0, vn=0;
  if (tid < NCHUNK){ vp = cpos[img*NCHUNK+tid]; vn = cneg[img*NCHUNK+tid]; }
  int lane = tid&63, w = tid>>6;
  int ip=vp, in_=vn;
  for (int off=1; off<64; off<<=1){
    int tp=__shfl_up(ip,off,64), tn=__shfl_up(in_,off,64);
    if (lane>=off){ ip+=tp; in_+=tn; }
  }
  if (lane==63){ s_p[w]=ip; s_n[w]=in_; }
  __syncthreads();
  int bp=0,bn=0;
  for (int ww=0; ww<w; ++ww){ bp+=s_p[ww]; bn+=s_n[ww]; }
  if (tid < NCHUNK){
    opos[img*NCHUNK+tid] = bp+ip-vp;
    oneg[img*NCHUNK+tid] = bn+in_-vn;
  }
  if (tid==0){
    int tp=0,tn=0;
    for (int ww=0; ww<8; ++ww){ tp+=s_p[ww]; tn+=s_n[ww]; }
    int np = tp<128?tp:128;
    quota[img*2]=np; quota[img*2+1]=256-np;
  }
}

// ---------------- L4: quota-sampled loss accumulation ---------------------
__global__ __launch_bounds__(256) void kL4_accum(
    const signed char* __restrict__ label, const float* __restrict__ nll_i,
    const float* __restrict__ loc_i, const int* __restrict__ opos,
    const int* __restrict__ oneg, const int* __restrict__ quota,
    float* __restrict__ acc) {
  __shared__ int s_wp[4], s_wn[4];
  __shared__ float s_red[8];
  int tid = threadIdx.x, img = blockIdx.y;
  int r = blockIdx.x*256 + tid;
  size_t o = (size_t)img*R_ANCH + r;
  int lab = label[o];
  bool pos = (lab==1), neg = (lab==0);
  u64 bp = __ballot(pos), bn = __ballot(neg);
  int wid = tid>>6, lane = tid&63;
  if (lane==0){ s_wp[wid]=__popcll(bp); s_wn[wid]=__popcll(bn); }
  __syncthreads();
  int pre_p = opos[img*NCHUNK + blockIdx.x];
  int pre_n = oneg[img*NCHUNK + blockIdx.x];
  for (int w=0; w<wid; ++w){ pre_p += s_wp[w]; pre_n += s_wn[w]; }
  u64 lm = (1ull<<lane) - 1ull;
  pre_p += __popcll(bp & lm);
  pre_n += __popcll(bn & lm);
  int np = quota[img*2], nn = quota[img*2+1];
  bool kp = pos && (pre_p < np);
  bool kn = neg && (pre_n < nn);
  float c_cls = (kp||kn) ? nll_i[o] : 0.0f;
  float c_loc = kp ? loc_i[o] : 0.0f;
  for (int of=32; of>0; of>>=1){
    c_cls += __shfl_down(c_cls, of, 64);
    c_loc += __shfl_down(c_loc, of, 64);
  }
  if (lane==0){ s_red[wid]=c_cls; s_red[4+wid]=c_loc; }
  __syncthreads();
  if (tid==0){
    float a = s_red[0]+s_red[1]+s_red[2]+s_red[3];
    float b = s_red[4]+s_red[5]+s_red[6]+s_red[7];
    if (a != 0.0f) atomicAdd(&acc[0], a);
    if (b != 0.0f) atomicAdd(&acc[1], b);
  }
}

// ---------------- F: stable compaction to 1000 + outputs ------------------
__global__ __launch_bounds__(256) void kF_final(
    const float* __restrict__ tb, const float* __restrict__ tu,
    const float* __restrict__ ts, const u64* __restrict__ keepw,
    const float* __restrict__ acc, float* __restrict__ out) {
  __shared__ int s_wk[4], s_wn[4];
  __shared__ int s_kc, s_runk, s_runn;
  int tid = threadIdx.x, img = blockIdx.x;
  int wid = tid>>6, lane = tid&63;
  const u64* kw = keepw + img*32;
  const float NEG_INF = __uint_as_float(0xff800000u);
  int cnt = 0;
  for (int c=0; c<8; ++c){
    int p = c*256 + tid;
    float4 b = ((const float4*)tb)[(size_t)img*PRE + p];
    bool kp = (p < PRE) && (((kw[p>>6]>>(p&63))&1ull)!=0ull) && (b.z > b.x) && (b.w > b.y);
    cnt += kp ? 1 : 0;
  }
  for (int of=32; of>0; of>>=1) cnt += __shfl_down(cnt, of, 64);
  if (lane==0) s_wk[wid] = cnt;
  __syncthreads();
  if (tid==0){ s_kc = s_wk[0]+s_wk[1]+s_wk[2]+s_wk[3]; s_runk=0; s_runn=0; }
  __syncthreads();
  int kc = s_kc;
  for (int c=0; c<8; ++c){
    int p = c*256 + tid;
    float4 b = ((const float4*)tb)[(size_t)img*PRE + p];
    bool kp = (p < PRE) && (((kw[p>>6]>>(p&63))&1ull)!=0ull) && (b.z > b.x) && (b.w > b.y);
    u64 bk = __ballot(kp), bn = __ballot(!kp);
    if (lane==0){ s_wk[wid]=__popcll(bk); s_wn[wid]=__popcll(bn); }
    __syncthreads();
    int pk = s_runk, pn = s_runn;
    for (int w=0; w<wid; ++w){ pk += s_wk[w]; pn += s_wn[w]; }
    u64 lm = (1ull<<lane) - 1ull;
    pk += __popcll(bk & lm);
    pn += __popcll(bn & lm);
    int slot = kp ? pk : (kc + pn);
    if (slot < POST && p < PRE){
      ((float4*)out)[img*POST + slot] = b;
      out[32000 + img*POST + slot] = kp ? ts[img*PRE + p] : NEG_INF;
      ((float2*)(out + 40000))[img*POST + slot] = ((const float2*)tu)[(size_t)img*PRE + p];
    }
    __syncthreads();
    if (tid==0){
      s_runk += s_wk[0]+s_wk[1]+s_wk[2]+s_wk[3];
      s_runn += s_wn[0]+s_wn[1]+s_wn[2]+s_wn[3];
    }
    __syncthreads();
  }
  if (img==0 && tid<2) out[56000+tid] = acc[tid] * (1.0f/2048.0f);
}

// ---------------- host-side launch ----------------------------------------
extern "C" void kernel_launch(void* const* d_in, const int* in_sizes, int n_in,
                              void* d_out, int out_size, void* d_ws, size_t ws_size,
                              hipStream_t stream) {
  const float* anchors = (const float*)d_in[0];
  const float* pi      = (const float*)d_in[1];
  const float* mu      = (const float*)d_in[2];
  const float* sigma   = (const float*)d_in[3];
  const float* deltas  = (const float*)d_in[4];
  const float* gt      = (const float*)d_in[5];
  float* out = (float*)d_out;

  char* ws = (char*)d_ws;
  size_t off = 0;
  auto alloc = [&](size_t bytes) -> void* {
    void* p = (void*)(ws + off);
    off += (bytes + 255) & ~(size_t)255;
    return p;
  };
  float* logits = (float*)alloc((size_t)NIMG*R_ANCH*4);
  float* epis   = (float*)alloc((size_t)NIMG*R_ANCH*4);
  float* alea   = (float*)alloc((size_t)NIMG*R_ANCH*4);
  float* tb     = (float*)alloc((size_t)NIMG*PRE*4*4);
  float* tu     = (float*)alloc((size_t)NIMG*PRE*2*4);
  float* ts     = (float*)alloc((size_t)NIMG*PRE*4);
  u64*   maskT  = (u64*)  alloc((size_t)NIMG*32*MROW*8);
  u64*   keepw  = (u64*)  alloc((size_t)NIMG*32*8);
  u64*   cand   = (u64*)  alloc((size_t)NIMG*4096*8);
  int*   cpos   = (int*)  alloc((size_t)NIMG*NCHUNK*4);
  int*   cneg   = (int*)  alloc((size_t)NIMG*NCHUNK*4);
  int*   opos   = (int*)  alloc((size_t)NIMG*NCHUNK*4);
  int*   oneg   = (int*)  alloc((size_t)NIMG*NCHUNK*4);
  int*   quota  = (int*)  alloc((size_t)NIMG*2*4);
  // ---- contiguous zero region (hist0..acc) ----
  size_t zstart = off;
  u32*   hist0  = (u32*)  alloc((size_t)NIMG*2048*4);
  u32*   hist1  = (u32*)  alloc((size_t)NIMG*2048*4);
  u32*   hist2  = (u32*)  alloc((size_t)NIMG*2048*4);
  u32*   gcnt   = (u32*)  alloc((size_t)NIMG*4);
  int*   best   = (int*)  alloc((size_t)NIMG*NGT*4);
  float* acc    = (float*)alloc(8);
  int zwords = (int)((off - zstart) / 4);
  // alias dead regions: logits/epis/alea last read in kSort; L2 runs after.
  signed char* label = (signed char*)logits;
  float* nll = epis;
  float* loc = alea;

  kZero<<<dim3(64), dim3(256), 0, stream>>>((u32*)(ws + zstart), zwords);
  kA_mdn<<<dim3(NCHUNK, NIMG), dim3(256), 0, stream>>>(pi, mu, sigma, logits, epis, alea, hist0);
  kP1<<<dim3(NBLK, NIMG), dim3(256), 0, stream>>>(logits, hist0, hist1);
  kP2<<<dim3(NBLK, NIMG), dim3(256), 0, stream>>>(logits, hist0, hist1, hist2);
  kGather<<<dim3(NBLK, NIMG), dim3(256), 0, stream>>>(logits, hist0, hist1, hist2, cand, gcnt);
  kSort<<<dim3(NIMG), dim3(1024), 0, stream>>>(cand, gcnt, epis, alea, deltas, anchors, tb, tu, ts);
  kD_mask<<<dim3(500, NIMG), dim3(256), 0, stream>>>(tb, maskT);
  kE_nms<<<dim3(NIMG), dim3(1024), 0, stream>>>(maskT, keepw);
  kL1_bestgt<<<dim3(NCHUNK, NIMG), dim3(256), 0, stream>>>(anchors, gt, best);
  kL2_label<<<dim3(NCHUNK, NIMG), dim3(256), 0, stream>>>(anchors, gt, best, pi, mu, sigma,
                                                          deltas, label, nll, loc, cpos, cneg);
  kL3_scan<<<dim3(NIMG), dim3(512), 0, stream>>>(cpos, cneg, opos, oneg, quota);
  kL4_accum<<<dim3(NCHUNK, NIMG), dim3(256), 0, stream>>>(label, nll, loc, opos, oneg, quota, acc);
  kF_final<<<dim3(NIMG), dim3(256), 0, stream>>>(tb, tu, ts, keepw, acc, out);
}

// Round 5
// 516.119 us; speedup vs baseline: 1.7125x; 1.0592x over previous
//
#include <hip/hip_runtime.h>
#include <cstdint>
#include <cstddef>

typedef unsigned long long u64;
typedef unsigned int u32;

#define R_ANCH 96000
#define NIMG   8
#define KMIX   5
#define PRE    2000
#define POST   1000
#define NGT    32
#define NCHUNK 375   // R_ANCH / 256
#define NBLK   48    // blocks per image for grid-stride scan kernels
#define MROW   2048  // transposed-mask row stride (padded PRE)

#define IMG_SZ        1280.0f
#define NMS_T         0.7f
#define SCALE_CLAMP_F 4.135166556742356f
#define HALF_L2PI     0.9189385332046727f

__device__ __forceinline__ u64 make_key(float s, int r) {
  u32 u = __float_as_uint(s);
  u = (u & 0x80000000u) ? ~u : (u | 0x80000000u);
  return ((u64)u << 32) | (u64)(0xFFFFFFFFu - (u32)r);
}

__device__ __forceinline__ float dec_score(u64 key) {
  u32 o = (u32)(key >> 32);
  u32 bits = (o & 0x80000000u) ? (o ^ 0x80000000u) : ~o;
  return __uint_as_float(bits);
}

// contract(off): kL1 and kL2 must produce bit-identical IoU values so that
// "iou >= best_gt - 1e-7" behaves exactly like the reference.
__device__ __forceinline__ float iou_pair(float a0,float a1,float a2,float a3,
                                          float b0,float b1,float b2,float b3) {
#pragma clang fp contract(off)
  float areaA = (a2-a0)*(a3-a1);
  float areaB = (b2-b0)*(b3-b1);
  float lx=fmaxf(a0,b0), ly=fmaxf(a1,b1);
  float rx=fminf(a2,b2), ry=fminf(a3,b3);
  float iw=fmaxf(rx-lx,0.0f), ih=fmaxf(ry-ly,0.0f);
  float inter=iw*ih;
  return inter / fmaxf(areaA+areaB-inter, 1e-9f);
}

__device__ __forceinline__ u64 shfl64_xor(u64 v, int m) {
  int lo = __shfl_xor((int)(u32)v, m, 64);
  int hi = __shfl_xor((int)(u32)(v>>32), m, 64);
  return ((u64)(u32)hi<<32)|(u64)(u32)lo;
}

// pick: from a 2048-bin histogram (bin d high = higher keys), find the bin
// containing the k-th largest key. Returns (d, k-within-bin, bin count).
// Must be called by exactly 256 threads. s_i >= 8 ints, s_u >= 3 u32.
__device__ __forceinline__ void pick2048(const u32* __restrict__ hist, int k,
                                         int* s_i, u32* s_u,
                                         int& d_out, int& k_out, u32& cnt_out) {
  int tid = threadIdx.x;
  int lane = tid & 63, w = tid >> 6;
  u32 h[8]; u32 ssum = 0;
#pragma unroll
  for (int i=0;i<8;++i){ h[i] = hist[2047 - (tid*8 + i)]; ssum += h[i]; }
  u32 incl = ssum;
  for (int off=1; off<64; off<<=1){
    u32 t = (u32)__shfl_up((int)incl, off, 64);
    if (lane >= off) incl += t;
  }
  if (lane==63) s_i[w] = (int)incl;
  __syncthreads();
  u32 base = 0;
  for (int ww=0; ww<w; ++ww) base += (u32)s_i[ww];
  u32 run = base + incl - ssum;              // exclusive prefix (descending keys)
#pragma unroll
  for (int i=0;i<8;++i){
    u32 nr = run + h[i];
    if (run < (u32)k && nr >= (u32)k){       // unique crossing thread
      s_u[0] = (u32)(2047 - (tid*8+i));
      s_u[1] = (u32)k - run;
      s_u[2] = h[i];
    }
    run = nr;
  }
  __syncthreads();
  d_out = (int)s_u[0]; k_out = (int)s_u[1]; cnt_out = s_u[2];
  __syncthreads();                           // allow s_u/s_i reuse by caller
}

// ---------------- zero: contiguous workspace region -----------------------
__global__ void kZero(u32* z, int nwords) {
  for (int i = blockIdx.x*256 + threadIdx.x; i < nwords; i += gridDim.x*256)
    z[i] = 0u;
}

// ---------------- A: MDN softmax moments + level-0 histogram --------------
__global__ __launch_bounds__(256) void kA_mdn(
    const float* __restrict__ pi, const float* __restrict__ mu,
    const float* __restrict__ sigma, float* __restrict__ logits,
    float* __restrict__ epis, float* __restrict__ alea,
    u32* __restrict__ hist0) {
  __shared__ u32 s_h[2048];
  int tid = threadIdx.x;
  int r = blockIdx.x*256 + tid;
  int img = blockIdx.y;
  for (int b=tid; b<2048; b+=256) s_h[b]=0u;
  size_t base = (size_t)img*KMIX*R_ANCH + r;
  float p[KMIX], m[KMIX], s[KMIX];
#pragma unroll
  for (int k=0;k<KMIX;k++){
    p[k]=pi[base+(size_t)k*R_ANCH];
    m[k]=mu[base+(size_t)k*R_ANCH];
    s[k]=sigma[base+(size_t)k*R_ANCH];
  }
  float mx = p[0];
#pragma unroll
  for (int k=1;k<KMIX;k++) mx = fmaxf(mx,p[k]);
  float e[KMIX]; float sum = 0.0f;
#pragma unroll
  for (int k=0;k<KMIX;k++){ e[k]=expf(p[k]-mx); sum += e[k]; }
  float w[KMIX]; float lg = 0.0f;
#pragma unroll
  for (int k=0;k<KMIX;k++){ w[k]=e[k]/sum; lg += w[k]*m[k]; }
  float ep = 0.0f, al = 0.0f;
#pragma unroll
  for (int k=0;k<KMIX;k++){ float d=m[k]-lg; ep += w[k]*d*d; al += w[k]*s[k]*s[k]; }
  size_t o = (size_t)img*R_ANCH + r;
  logits[o]=lg; epis[o]=ep; alea[o]=al;
  __syncthreads();                           // s_h zero complete
  u64 key = make_key(lg, r);
  atomicAdd(&s_h[(u32)(key>>53)], 1u);
  __syncthreads();
  for (int b=tid; b<2048; b+=256){ u32 v=s_h[b]; if(v) atomicAdd(&hist0[img*2048+b], v); }
}

// ---------------- P1: refine level-1 histogram (if needed) ----------------
__global__ __launch_bounds__(256) void kP1(const float* __restrict__ logits,
                                           const u32* __restrict__ hist0,
                                           u32* __restrict__ hist1) {
  __shared__ u32 s_h[2048];
  __shared__ int s_i[8]; __shared__ u32 s_u[3];
  int img = blockIdx.y, tid = threadIdx.x;
  int d0,k0; u32 c0;
  pick2048(hist0 + img*2048, PRE, s_i, s_u, d0,k0,c0);
  if (c0 <= 2048u) return;                   // block-uniform
  for (int b=tid; b<2048; b+=256) s_h[b]=0u;
  __syncthreads();
  const float* sc = logits + (size_t)img*R_ANCH;
  for (int r = blockIdx.x*256 + tid; r < R_ANCH; r += NBLK*256){
    u64 key = make_key(sc[r], r);
    if ((int)(key>>53) == d0) atomicAdd(&s_h[(u32)(key>>42)&2047u], 1u);
  }
  __syncthreads();
  for (int b=tid; b<2048; b+=256){ u32 v=s_h[b]; if(v) atomicAdd(&hist1[img*2048+b], v); }
}

// ---------------- P2: refine level-2 histogram (rarely needed) ------------
__global__ __launch_bounds__(256) void kP2(const float* __restrict__ logits,
                                           const u32* __restrict__ hist0,
                                           const u32* __restrict__ hist1,
                                           u32* __restrict__ hist2) {
  __shared__ u32 s_h[2048];
  __shared__ int s_i[8]; __shared__ u32 s_u[3];
  int img = blockIdx.y, tid = threadIdx.x;
  int d0,k0; u32 c0;
  pick2048(hist0 + img*2048, PRE, s_i, s_u, d0,k0,c0);
  if (c0 <= 2048u) return;
  int d1,k1; u32 c1;
  pick2048(hist1 + img*2048, k0, s_i, s_u, d1,k1,c1);
  if (c1 <= 2048u) return;
  u64 p1 = ((u64)d0<<11) | (u64)d1;
  for (int b=tid; b<2048; b+=256) s_h[b]=0u;
  __syncthreads();
  const float* sc = logits + (size_t)img*R_ANCH;
  for (int r = blockIdx.x*256 + tid; r < R_ANCH; r += NBLK*256){
    u64 key = make_key(sc[r], r);
    if ((key>>42) == p1) atomicAdd(&s_h[(u32)(key>>31)&2047u], 1u);
  }
  __syncthreads();
  for (int b=tid; b<2048; b+=256){ u32 v=s_h[b]; if(v) atomicAdd(&hist2[img*2048+b], v); }
}

// ---------------- G: gather candidates >= bin lower bound -----------------
__global__ __launch_bounds__(256) void kGather(const float* __restrict__ logits,
    const u32* __restrict__ hist0, const u32* __restrict__ hist1,
    const u32* __restrict__ hist2, u64* __restrict__ cand, u32* __restrict__ gcnt) {
  __shared__ int s_i[8]; __shared__ u32 s_u[3];
  int img = blockIdx.y, tid = threadIdx.x;
  int d,kk; u32 c;
  pick2048(hist0 + img*2048, PRE, s_i, s_u, d,kk,c);
  u64 p = (u64)d; int L = 0;
  if (c > 2048u){
    pick2048(hist1 + img*2048, kk, s_i, s_u, d,kk,c);
    p = (p<<11)|(u64)d; L = 1;
    if (c > 2048u){
      pick2048(hist2 + img*2048, kk, s_i, s_u, d,kk,c);
      p = (p<<11)|(u64)d; L = 2;
    }
  }
  u64 T = p << (64 - 11*(L+1));              // candidates = (2000-kk)+c <= 4047
  const float* sc = logits + (size_t)img*R_ANCH;
  int lane = tid & 63;
  for (int r = blockIdx.x*256 + tid; r < R_ANCH; r += NBLK*256){
    u64 key = make_key(sc[r], r);
    bool take = (key >= T);
    u64 b = __ballot(take);
    if (b){
      u32 base = 0;
      if (lane==0) base = atomicAdd(&gcnt[img], (u32)__popcll(b));
      base = (u32)__shfl((int)base, 0, 64);
      if (take){
        u32 pos = base + (u32)__popcll(b & ((1ull<<lane)-1ull));
        if (pos < 4096u) cand[(size_t)img*4096 + pos] = key;
      }
    }
  }
}

// ---------------- S: bitonic sort 4096 + exact epilogue -------------------
__global__ __launch_bounds__(1024) void kSort(
    const u64* __restrict__ cand, const u32* __restrict__ gcnt,
    const float* __restrict__ epis, const float* __restrict__ alea,
    const float* __restrict__ deltas, const float* __restrict__ anchors,
    float* __restrict__ tb, float* __restrict__ tu, float* __restrict__ ts) {
  __shared__ u64 s_keys[4096];               // 32 KB
  int tid = threadIdx.x, img = blockIdx.x;
  u32 cnt = gcnt[img];
  if (cnt > 4096u) cnt = 4096u;
  for (int i=tid; i<4096; i+=1024)
    s_keys[i] = (i < (int)cnt) ? cand[(size_t)img*4096 + i] : 0ull;
  __syncthreads();
  for (u32 kk=2; kk<=4096; kk<<=1){
    for (u32 j=kk>>1; j>0; j>>=1){
#pragma unroll
      for (int q0=0; q0<2; ++q0){            // 2048 disjoint pairs / 1024 thr
        u32 q = (u32)tid + (u32)q0*1024u;
        u32 i = ((q & ~(j-1u)) << 1) | (q & (j-1u));
        u32 pi_ = i | j;
        u64 a = s_keys[i], b = s_keys[pi_];
        bool descSeg = ((i & kk) == 0u);
        bool sw = descSeg ? (a < b) : (a > b);
        if (sw){ s_keys[i]=b; s_keys[pi_]=a; }
      }
      __syncthreads();
    }
  }
  for (int p=tid; p<PRE; p+=1024){
    u64 key = s_keys[p];
    u32 idx = 0xFFFFFFFFu - (u32)(key & 0xFFFFFFFFull);
    ts[img*PRE + p] = dec_score(key);
    float4 a = ((const float4*)anchors)[idx];
    float4 d = ((const float4*)deltas)[(size_t)img*R_ANCH + idx];
    float w = a.z - a.x, h = a.w - a.y;
    float cx = a.x + 0.5f*w, cy = a.y + 0.5f*h;
    float dw = fminf(d.z, SCALE_CLAMP_F), dh = fminf(d.w, SCALE_CLAMP_F);
    float pcx = d.x*w + cx, pcy = d.y*h + cy;
    float pw = expf(dw)*w, ph = expf(dh)*h;
    float x0 = fminf(fmaxf(pcx - 0.5f*pw, 0.0f), IMG_SZ);
    float y0 = fminf(fmaxf(pcy - 0.5f*ph, 0.0f), IMG_SZ);
    float x1 = fminf(fmaxf(pcx + 0.5f*pw, 0.0f), IMG_SZ);
    float y1 = fminf(fmaxf(pcy + 0.5f*ph, 0.0f), IMG_SZ);
    ((float4*)tb)[(size_t)img*PRE + p] = make_float4(x0,y0,x1,y1);
    size_t o = (size_t)img*R_ANCH + idx;
    ((float2*)tu)[(size_t)img*PRE + p] = make_float2(epis[o], alea[o]);
  }
}

// ---------------- D: suppression bitmask, TRANSPOSED + diag columns ------
// maskT[img][word][row]: coalesced for kE's per-word loads.
// diagT[img][i]: COLUMN i of the in-tile diagonal block, i.e. bits b with
// b<i (same tile) and IoU(b,i)>0.7 — by symmetry: ballot(v>T && j<i) on the
// diagonal word. This feeds kE's ballot-based chain (no dynamic shuffles).
__global__ __launch_bounds__(256) void kD_mask(const float* __restrict__ tb,
                                               u64* __restrict__ maskT,
                                               u64* __restrict__ diagT) {
  __shared__ float4 s_box[PRE];              // 32 KB
  int tid = threadIdx.x, img = blockIdx.y;
  const float4* tbi = (const float4*)tb + (size_t)img*PRE;
  for (int q=tid; q<PRE; q+=256) s_box[q] = tbi[q];
  __syncthreads();
  int wave = tid >> 6, lane = tid & 63;
  int i = blockIdx.x*4 + wave;               // gridDim.x = 500
  float4 A = s_box[i];
  u64* MT = maskT + (size_t)img*32*MROW;
  int wdiag = i>>6;
  for (int w = wdiag; w<32; ++w){
    int j = w*64 + lane;
    float v = -1.0f;
    if (j < PRE){
      float4 B = s_box[j];
      v = iou_pair(A.x,A.y,A.z,A.w, B.x,B.y,B.z,B.w);
    }
    u64 m = __ballot((v > NMS_T) && (j > i));
    if (lane==0) MT[(size_t)w*MROW + i] = m;
    if (w == wdiag){
      u64 mlow = __ballot((v > NMS_T) && (j < i));
      if (lane==0) diagT[(size_t)img*MROW + i] = mlow;
    }
  }
}

// ---------------- E: greedy NMS, ballot-chain (no dynamic shuffles) -------
__global__ __launch_bounds__(1024) void kE_nms(const u64* __restrict__ maskT,
                                               const u64* __restrict__ diagT,
                                               u64* __restrict__ keep) {
  __shared__ u64 s_sup[32];
  __shared__ u64 s_K;
  int img = blockIdx.x;
  int tid = threadIdx.x, wv = tid>>6, lane = tid&63;
  if (tid < 32) s_sup[tid] = 0ull;
  __syncthreads();
  const u64* MT = maskT + (size_t)img*32*MROW;
  const u64* DG = diagT + (size_t)img*MROW;
  for (int t=0; t<32; ++t){
    int base = t*64;
    int cnt = min(64, PRE - base);           // last tile: 16
    // issue phase-B loads early; masked by `kept` after the chain.
    // rows >= PRE read uninitialized words but K never keeps them.
    int w0 = wv, w1 = wv + 16;
    u64 v0 = (w0 > t) ? MT[(size_t)w0*MROW + base + lane] : 0ull;
    u64 v1 = (w1 > t) ? MT[(size_t)w1*MROW + base + lane] : 0ull;
    if (wv == 0){
      // chain: lane j holds in-tile COLUMN j; row b recovered wave-wide by
      // ballot (v_cmp -> SGPR, ~5cyc, independent of the scalar W chain).
      u64 col = (lane < cnt) ? DG[base + lane] : 0ull;
      u64 W = s_sup[t];                      // wave-uniform
      u64 K = 0ull;
      for (int b=0; b<cnt; ++b){
        u64 rowb = __ballot((col>>b)&1ull);  // in-tile victims of row b
        if (!((W>>b)&1ull)){ K |= (1ull<<b); W |= rowb; }
      }
      if (lane==0){ s_K = K; s_sup[t] = W; } // final word t
    }
    __syncthreads();
    u64 K = s_K;
    bool kept = ((K>>lane)&1ull) != 0ull;
    if (!kept){ v0 = 0ull; v1 = 0ull; }
    if (w0 > t && __ballot(v0 != 0ull)){
      v0 |= shfl64_xor(v0, 1);  v0 |= shfl64_xor(v0, 2);
      v0 |= shfl64_xor(v0, 4);  v0 |= shfl64_xor(v0, 8);
      v0 |= shfl64_xor(v0, 16); v0 |= shfl64_xor(v0, 32);
      if (lane==0) s_sup[w0] |= v0;
    }
    if (w1 > t && __ballot(v1 != 0ull)){
      v1 |= shfl64_xor(v1, 1);  v1 |= shfl64_xor(v1, 2);
      v1 |= shfl64_xor(v1, 4);  v1 |= shfl64_xor(v1, 8);
      v1 |= shfl64_xor(v1, 16); v1 |= shfl64_xor(v1, 32);
      if (lane==0) s_sup[w1] |= v1;
    }
    __syncthreads();
  }
  if (tid < 32) keep[img*32 + tid] = ~s_sup[tid];
}

// ---------------- L1: best IoU per GT over all anchors --------------------
__global__ __launch_bounds__(256) void kL1_bestgt(const float* __restrict__ anchors,
                                                  const float* __restrict__ gt,
                                                  int* __restrict__ best) {
  __shared__ float s_gt[NGT*4];
  __shared__ int s_best[NGT];
  int tid = threadIdx.x, img = blockIdx.y;
  int r = blockIdx.x*256 + tid;
  if (tid < NGT*4) s_gt[tid] = gt[img*NGT*4 + tid];
  if (tid < NGT) s_best[tid] = 0;
  __syncthreads();
  float4 a = ((const float4*)anchors)[r];
#pragma unroll 4
  for (int g=0; g<NGT; ++g){
    float v = iou_pair(s_gt[g*4],s_gt[g*4+1],s_gt[g*4+2],s_gt[g*4+3],
                       a.x,a.y,a.z,a.w);
    if (v > __int_as_float(s_best[g])) atomicMax(&s_best[g], __float_as_int(v));
  }
  __syncthreads();
  if (tid < NGT) atomicMax(&best[img*NGT + tid], s_best[tid]);
}

// ---------------- L2: labels, NLL, L1-loc, per-chunk pos/neg counts -------
__global__ __launch_bounds__(256) void kL2_label(
    const float* __restrict__ anchors, const float* __restrict__ gt,
    const int* __restrict__ best, const float* __restrict__ pi,
    const float* __restrict__ mu, const float* __restrict__ sigma,
    const float* __restrict__ deltas,
    signed char* __restrict__ label, float* __restrict__ nll_o,
    float* __restrict__ loc_o, int* __restrict__ cpos, int* __restrict__ cneg) {
  __shared__ float s_gt[NGT*4];
  __shared__ float s_bg[NGT];
  __shared__ int s_w[8];
  int tid = threadIdx.x, img = blockIdx.y;
  int r = blockIdx.x*256 + tid;
  if (tid < NGT*4) s_gt[tid] = gt[img*NGT*4 + tid];
  if (tid < NGT) s_bg[tid] = __int_as_float(best[img*NGT + tid]);
  __syncthreads();
  float4 a = ((const float4*)anchors)[r];
  float vbest = -1.0f; int idx = 0; bool lq = false;
#pragma unroll 4
  for (int g=0; g<NGT; ++g){
    float v = iou_pair(s_gt[g*4],s_gt[g*4+1],s_gt[g*4+2],s_gt[g*4+3],
                       a.x,a.y,a.z,a.w);
    if (v > vbest){ vbest = v; idx = g; }
    float bg = s_bg[g];
    lq = lq || ((v >= bg - 1e-7f) && (bg > 0.0f));
  }
  int lab = lq ? 1 : (vbest >= 0.7f ? 1 : (vbest >= 0.3f ? -1 : 0));
  size_t base = (size_t)img*KMIX*R_ANCH + r;
  float p[KMIX], m[KMIX], s[KMIX];
#pragma unroll
  for (int k=0;k<KMIX;k++){
    p[k]=pi[base+(size_t)k*R_ANCH];
    m[k]=mu[base+(size_t)k*R_ANCH];
    s[k]=sigma[base+(size_t)k*R_ANCH];
  }
  float mx = p[0];
#pragma unroll
  for (int k=1;k<KMIX;k++) mx = fmaxf(mx,p[k]);
  float sum = 0.0f;
#pragma unroll
  for (int k=0;k<KMIX;k++) sum += expf(p[k]-mx);
  float lsum = logf(sum);
  float t_ = fminf(fmaxf(vbest, 0.0f), 1.0f);
  float comp[KMIX];
#pragma unroll
  for (int k=0;k<KMIX;k++){
    float z = (t_ - m[k]) / s[k];
    comp[k] = (p[k]-mx-lsum) - 0.5f*z*z - logf(s[k]) - HALF_L2PI;
  }
  float cm = comp[0];
#pragma unroll
  for (int k=1;k<KMIX;k++) cm = fmaxf(cm, comp[k]);
  float se = 0.0f;
#pragma unroll
  for (int k=0;k<KMIX;k++) se += expf(comp[k]-cm);
  float nll = -(cm + logf(se));
  const float* gb = &s_gt[idx*4];
  float sw = a.z-a.x, sh = a.w-a.y;
  float scx = a.x+0.5f*sw, scy = a.y+0.5f*sh;
  float tw = gb[2]-gb[0], th = gb[3]-gb[1];
  float tcx = gb[0]+0.5f*tw, tcy = gb[1]+0.5f*th;
  float4 d = ((const float4*)deltas)[(size_t)img*R_ANCH + r];
  float loc = fabsf(d.x-(tcx-scx)/sw) + fabsf(d.y-(tcy-scy)/sh)
            + fabsf(d.z-logf(tw/sw)) + fabsf(d.w-logf(th/sh));
  size_t o = (size_t)img*R_ANCH + r;
  label[o] = (signed char)lab; nll_o[o] = nll; loc_o[o] = loc;
  u64 bp = __ballot(lab==1), bn = __ballot(lab==0);
  int wid = tid>>6, lane = tid&63;
  if (lane==0){ s_w[wid*2]=__popcll(bp); s_w[wid*2+1]=__popcll(bn); }
  __syncthreads();
  if (tid==0){
    cpos[img*NCHUNK + blockIdx.x] = s_w[0]+s_w[2]+s_w[4]+s_w[6];
    cneg[img*NCHUNK + blockIdx.x] = s_w[1]+s_w[3]+s_w[5]+s_w[7];
  }
}

// ---------------- L3: parallel per-image chunk-offset scan + quotas -------
__global__ __launch_bounds__(512) void kL3_scan(const int* __restrict__ cpos,
                                                const int* __restrict__ cneg,
                                                int* __restrict__ opos,
                                                int* __restrict__ oneg,
                                                int* __restrict__ quota) {
  __shared__ int s_p[8], s_n[8];
  int img = blockIdx.x, tid = threadIdx.x;
  int vp=0, vn=0;
  if (tid < NCHUNK){ vp = cpos[img*NCHUNK+tid]; vn = cneg[img*NCHUNK+tid]; }
  int lane = tid&63, w = tid>>6;
  int ip=vp, in_=vn;
  for (int off=1; off<64; off<<=1){
    int tp=__shfl_up(ip,off,64), tn=__shfl_up(in_,off,64);
    if (lane>=off){ ip+=tp; in_+=tn; }
  }
  if (lane==63){ s_p[w]=ip; s_n[w]=in_; }
  __syncthreads();
  int bp=0,bn=0;
  for (int ww=0; ww<w; ++ww){ bp+=s_p[ww]; bn+=s_n[ww]; }
  if (tid < NCHUNK){
    opos[img*NCHUNK+tid] = bp+ip-vp;
    oneg[img*NCHUNK+tid] = bn+in_-vn;
  }
  if (tid==0){
    int tp=0,tn=0;
    for (int ww=0; ww<8; ++ww){ tp+=s_p[ww]; tn+=s_n[ww]; }
    int np = tp<128?tp:128;
    quota[img*2]=np; quota[img*2+1]=256-np;
  }
}

// ---------------- L4: quota-sampled loss accumulation ---------------------
__global__ __launch_bounds__(256) void kL4_accum(
    const signed char* __restrict__ label, const float* __restrict__ nll_i,
    const float* __restrict__ loc_i, const int* __restrict__ opos,
    const int* __restrict__ oneg, const int* __restrict__ quota,
    float* __restrict__ acc) {
  __shared__ int s_wp[4], s_wn[4];
  __shared__ float s_red[8];
  int tid = threadIdx.x, img = blockIdx.y;
  int r = blockIdx.x*256 + tid;
  size_t o = (size_t)img*R_ANCH + r;
  int lab = label[o];
  bool pos = (lab==1), neg = (lab==0);
  u64 bp = __ballot(pos), bn = __ballot(neg);
  int wid = tid>>6, lane = tid&63;
  if (lane==0){ s_wp[wid]=__popcll(bp); s_wn[wid]=__popcll(bn); }
  __syncthreads();
  int pre_p = opos[img*NCHUNK + blockIdx.x];
  int pre_n = oneg[img*NCHUNK + blockIdx.x];
  for (int w=0; w<wid; ++w){ pre_p += s_wp[w]; pre_n += s_wn[w]; }
  u64 lm = (1ull<<lane) - 1ull;
  pre_p += __popcll(bp & lm);
  pre_n += __popcll(bn & lm);
  int np = quota[img*2], nn = quota[img*2+1];
  bool kp = pos && (pre_p < np);
  bool kn = neg && (pre_n < nn);
  float c_cls = (kp||kn) ? nll_i[o] : 0.0f;
  float c_loc = kp ? loc_i[o] : 0.0f;
  for (int of=32; of>0; of>>=1){
    c_cls += __shfl_down(c_cls, of, 64);
    c_loc += __shfl_down(c_loc, of, 64);
  }
  if (lane==0){ s_red[wid]=c_cls; s_red[4+wid]=c_loc; }
  __syncthreads();
  if (tid==0){
    float a = s_red[0]+s_red[1]+s_red[2]+s_red[3];
    float b = s_red[4]+s_red[5]+s_red[6]+s_red[7];
    if (a != 0.0f) atomicAdd(&acc[0], a);
    if (b != 0.0f) atomicAdd(&acc[1], b);
  }
}

// ---------------- F: stable compaction to 1000 + outputs ------------------
__global__ __launch_bounds__(256) void kF_final(
    const float* __restrict__ tb, const float* __restrict__ tu,
    const float* __restrict__ ts, const u64* __restrict__ keepw,
    const float* __restrict__ acc, float* __restrict__ out) {
  __shared__ int s_wk[4], s_wn[4];
  __shared__ int s_kc, s_runk, s_runn;
  int tid = threadIdx.x, img = blockIdx.x;
  int wid = tid>>6, lane = tid&63;
  const u64* kw = keepw + img*32;
  const float NEG_INF = __uint_as_float(0xff800000u);
  int cnt = 0;
  for (int c=0; c<8; ++c){
    int p = c*256 + tid;
    float4 b = ((const float4*)tb)[(size_t)img*PRE + p];
    bool kp = (p < PRE) && (((kw[p>>6]>>(p&63))&1ull)!=0ull) && (b.z > b.x) && (b.w > b.y);
    cnt += kp ? 1 : 0;
  }
  for (int of=32; of>0; of>>=1) cnt += __shfl_down(cnt, of, 64);
  if (lane==0) s_wk[wid] = cnt;
  __syncthreads();
  if (tid==0){ s_kc = s_wk[0]+s_wk[1]+s_wk[2]+s_wk[3]; s_runk=0; s_runn=0; }
  __syncthreads();
  int kc = s_kc;
  for (int c=0; c<8; ++c){
    int p = c*256 + tid;
    float4 b = ((const float4*)tb)[(size_t)img*PRE + p];
    bool kp = (p < PRE) && (((kw[p>>6]>>(p&63))&1ull)!=0ull) && (b.z > b.x) && (b.w > b.y);
    u64 bk = __ballot(kp), bn = __ballot(!kp);
    if (lane==0){ s_wk[wid]=__popcll(bk); s_wn[wid]=__popcll(bn); }
    __syncthreads();
    int pk = s_runk, pn = s_runn;
    for (int w=0; w<wid; ++w){ pk += s_wk[w]; pn += s_wn[w]; }
    u64 lm = (1ull<<lane) - 1ull;
    pk += __popcll(bk & lm);
    pn += __popcll(bn & lm);
    int slot = kp ? pk : (kc + pn);
    if (slot < POST && p < PRE){
      ((float4*)out)[img*POST + slot] = b;
      out[32000 + img*POST + slot] = kp ? ts[img*PRE + p] : NEG_INF;
      ((float2*)(out + 40000))[img*POST + slot] = ((const float2*)tu)[(size_t)img*PRE + p];
    }
    __syncthreads();
    if (tid==0){
      s_runk += s_wk[0]+s_wk[1]+s_wk[2]+s_wk[3];
      s_runn += s_wn[0]+s_wn[1]+s_wn[2]+s_wn[3];
    }
    __syncthreads();
  }
  if (img==0 && tid<2) out[56000+tid] = acc[tid] * (1.0f/2048.0f);
}

// ---------------- host-side launch ----------------------------------------
extern "C" void kernel_launch(void* const* d_in, const int* in_sizes, int n_in,
                              void* d_out, int out_size, void* d_ws, size_t ws_size,
                              hipStream_t stream) {
  const float* anchors = (const float*)d_in[0];
  const float* pi      = (const float*)d_in[1];
  const float* mu      = (const float*)d_in[2];
  const float* sigma   = (const float*)d_in[3];
  const float* deltas  = (const float*)d_in[4];
  const float* gt      = (const float*)d_in[5];
  float* out = (float*)d_out;

  char* ws = (char*)d_ws;
  size_t off = 0;
  auto alloc = [&](size_t bytes) -> void* {
    void* p = (void*)(ws + off);
    off += (bytes + 255) & ~(size_t)255;
    return p;
  };
  float* logits = (float*)alloc((size_t)NIMG*R_ANCH*4);
  float* epis   = (float*)alloc((size_t)NIMG*R_ANCH*4);
  float* alea   = (float*)alloc((size_t)NIMG*R_ANCH*4);
  float* tb     = (float*)alloc((size_t)NIMG*PRE*4*4);
  float* tu     = (float*)alloc((size_t)NIMG*PRE*2*4);
  float* ts     = (float*)alloc((size_t)NIMG*PRE*4);
  u64*   maskT  = (u64*)  alloc((size_t)NIMG*32*MROW*8);
  u64*   diagT  = (u64*)  alloc((size_t)NIMG*MROW*8);
  u64*   keepw  = (u64*)  alloc((size_t)NIMG*32*8);
  u64*   cand   = (u64*)  alloc((size_t)NIMG*4096*8);
  int*   cpos   = (int*)  alloc((size_t)NIMG*NCHUNK*4);
  int*   cneg   = (int*)  alloc((size_t)NIMG*NCHUNK*4);
  int*   opos   = (int*)  alloc((size_t)NIMG*NCHUNK*4);
  int*   oneg   = (int*)  alloc((size_t)NIMG*NCHUNK*4);
  int*   quota  = (int*)  alloc((size_t)NIMG*2*4);
  // ---- contiguous zero region (hist0..acc) ----
  size_t zstart = off;
  u32*   hist0  = (u32*)  alloc((size_t)NIMG*2048*4);
  u32*   hist1  = (u32*)  alloc((size_t)NIMG*2048*4);
  u32*   hist2  = (u32*)  alloc((size_t)NIMG*2048*4);
  u32*   gcnt   = (u32*)  alloc((size_t)NIMG*4);
  int*   best   = (int*)  alloc((size_t)NIMG*NGT*4);
  float* acc    = (float*)alloc(8);
  int zwords = (int)((off - zstart) / 4);
  // alias dead regions: logits/epis/alea last read in kSort; L2 runs after.
  signed char* label = (signed char*)logits;
  float* nll = epis;
  float* loc = alea;

  kZero<<<dim3(64), dim3(256), 0, stream>>>((u32*)(ws + zstart), zwords);
  kA_mdn<<<dim3(NCHUNK, NIMG), dim3(256), 0, stream>>>(pi, mu, sigma, logits, epis, alea, hist0);
  kP1<<<dim3(NBLK, NIMG), dim3(256), 0, stream>>>(logits, hist0, hist1);
  kP2<<<dim3(NBLK, NIMG), dim3(256), 0, stream>>>(logits, hist0, hist1, hist2);
  kGather<<<dim3(NBLK, NIMG), dim3(256), 0, stream>>>(logits, hist0, hist1, hist2, cand, gcnt);
  kSort<<<dim3(NIMG), dim3(1024), 0, stream>>>(cand, gcnt, epis, alea, deltas, anchors, tb, tu, ts);
  kD_mask<<<dim3(500, NIMG), dim3(256), 0, stream>>>(tb, maskT, diagT);
  kE_nms<<<dim3(NIMG), dim3(1024), 0, stream>>>(maskT, diagT, keepw);
  kL1_bestgt<<<dim3(NCHUNK, NIMG), dim3(256), 0, stream>>>(anchors, gt, best);
  kL2_label<<<dim3(NCHUNK, NIMG), dim3(256), 0, stream>>>(anchors, gt, best, pi, mu, sigma,
                                                          deltas, label, nll, loc, cpos, cneg);
  kL3_scan<<<dim3(NIMG), dim3(512), 0, stream>>>(cpos, cneg, opos, oneg, quota);
  kL4_accum<<<dim3(NCHUNK, NIMG), dim3(256), 0, stream>>>(label, nll, loc, opos, oneg, quota, acc);
  kF_final<<<dim3(NIMG), dim3(256), 0, stream>>>(tb, tu, ts, keepw, acc, out);
}